// Round 2
// baseline (2243.209 us; speedup 1.0000x reference)
//
#include <hip/hip_runtime.h>
#include <cstdint>
#include <cstddef>

#define NN 100000
#define NE 1000000
#define FIN 128
#define HD 256
#define NG 64
#define BNEPS 1e-5f

// ---------- bf16<->f32 helpers (storage type ST is float or ushort[bf16]) ----------

__device__ inline float b2f(unsigned short u) {
    union { float f; unsigned int i; } x; x.i = ((unsigned int)u) << 16; return x.f;
}
__device__ inline unsigned short f2b(float f) {
    union { float f; unsigned int i; } x; x.f = f;
    unsigned int r = x.i + 0x7FFFu + ((x.i >> 16) & 1u);
    return (unsigned short)(r >> 16);
}
__device__ inline float  ld1(const float* p) { return *p; }
__device__ inline float  ld1(const unsigned short* p) { return b2f(*p); }
__device__ inline float4 ld4v(const float* p) { return *(const float4*)p; }
__device__ inline float4 ld4v(const unsigned short* p) {
    ushort4 u = *(const ushort4*)p;
    return make_float4(b2f(u.x), b2f(u.y), b2f(u.z), b2f(u.w));
}
__device__ inline float2 ld2v(const float* p) { return *(const float2*)p; }
__device__ inline float2 ld2v(const unsigned short* p) {
    ushort2 u = *(const ushort2*)p;
    return make_float2(b2f(u.x), b2f(u.y));
}
__device__ inline void st4v(float* p, float4 v) { *(float4*)p = v; }
__device__ inline void st4v(unsigned short* p, float4 v) {
    ushort4 u; u.x = f2b(v.x); u.y = f2b(v.y); u.z = f2b(v.z); u.w = f2b(v.w);
    *(ushort4*)p = u;
}
__device__ inline void st2v(float* p, float2 v) { *(float2*)p = v; }
__device__ inline void st2v(unsigned short* p, float2 v) {
    ushort2 u; u.x = f2b(v.x); u.y = f2b(v.y);
    *(ushort2*)p = u;
}

// ---------------- graph preprocessing ----------------

__global__ __launch_bounds__(256) void count_deg_k(const int* __restrict__ dst, int* __restrict__ cnt) {
    int e = blockIdx.x * 256 + threadIdx.x;
    if (e < NE) atomicAdd(&cnt[dst[e]], 1);
}

__global__ __launch_bounds__(256) void node_prep_k(const int* __restrict__ cnt,
                                                   float* __restrict__ dis, float* __restrict__ selfw) {
    int i = blockIdx.x * 256 + threadIdx.x;
    if (i < NN) {
        float d = (float)cnt[i] + 1.0f;
        dis[i] = rsqrtf(d);
        selfw[i] = 1.0f / d;
    }
}

__global__ __launch_bounds__(1024) void scan_reduce_k(const int* __restrict__ cnt, int* __restrict__ partials) {
    __shared__ int sh[1024];
    int i = blockIdx.x * 1024 + threadIdx.x;
    sh[threadIdx.x] = (i < NN) ? cnt[i] : 0;
    __syncthreads();
    for (int off = 512; off > 0; off >>= 1) {
        if (threadIdx.x < off) sh[threadIdx.x] += sh[threadIdx.x + off];
        __syncthreads();
    }
    if (threadIdx.x == 0) partials[blockIdx.x] = sh[0];
}

__global__ void scan_partials_k(int* partials, int nb) {
    if (threadIdx.x == 0 && blockIdx.x == 0) {
        int run = 0;
        for (int b = 0; b < nb; b++) { int v = partials[b]; partials[b] = run; run += v; }
    }
}

__global__ __launch_bounds__(1024) void scan_write_k(const int* __restrict__ cnt,
                                                     const int* __restrict__ partials,
                                                     int* __restrict__ rowptr) {
    __shared__ int sh[1024];
    int i = blockIdx.x * 1024 + threadIdx.x;
    int v = (i < NN) ? cnt[i] : 0;
    sh[threadIdx.x] = v;
    __syncthreads();
    for (int off = 1; off < 1024; off <<= 1) {
        int t = (threadIdx.x >= off) ? sh[threadIdx.x - off] : 0;
        __syncthreads();
        sh[threadIdx.x] += t;
        __syncthreads();
    }
    if (i < NN) rowptr[i] = partials[blockIdx.x] + sh[threadIdx.x] - v;
    if (i == NN - 1) rowptr[NN] = partials[blockIdx.x] + sh[threadIdx.x];
}

__global__ __launch_bounds__(256) void fill_csr_k(const int* __restrict__ src, const int* __restrict__ dst,
                                                  const int* __restrict__ rowptr, int* __restrict__ cursor,
                                                  const float* __restrict__ dis,
                                                  int* __restrict__ csr_src, float* __restrict__ csr_w) {
    int e = blockIdx.x * 256 + threadIdx.x;
    if (e < NE) {
        int d = dst[e], s = src[e];
        int pos = rowptr[d] + atomicAdd(&cursor[d], 1);
        csr_src[pos] = s;
        csr_w[pos] = dis[s] * dis[d];
    }
}

// ---------------- SpMM: z[i,:] = selfw[i]*h[i,:] + sum_e w_e * h[src_e,:] ----------------

template<typename SIN, typename SOUT, int COLS>
__global__ __launch_bounds__(256) void spmm_k(const SIN* __restrict__ h,
                                              const int* __restrict__ rowptr,
                                              const int* __restrict__ csr_src,
                                              const float* __restrict__ csr_w,
                                              const float* __restrict__ selfw,
                                              SOUT* __restrict__ z) {
    const int lane = threadIdx.x & 63;
    const int row = blockIdx.x * 4 + (threadIdx.x >> 6);
    if (row >= NN) return;
    if constexpr (COLS == 256) {
        float4 a = ld4v(h + (size_t)row * COLS + lane * 4);
        float sw = selfw[row];
        float4 acc = make_float4(a.x * sw, a.y * sw, a.z * sw, a.w * sw);
        const int e1 = rowptr[row + 1];
        for (int e = rowptr[row]; e < e1; e++) {
            int s = csr_src[e];
            float w = csr_w[e];
            float4 hv = ld4v(h + (size_t)s * COLS + lane * 4);
            acc.x += w * hv.x; acc.y += w * hv.y; acc.z += w * hv.z; acc.w += w * hv.w;
        }
        st4v(z + (size_t)row * COLS + lane * 4, acc);
    } else {
        float2 a = ld2v(h + (size_t)row * COLS + lane * 2);
        float sw = selfw[row];
        float2 acc = make_float2(a.x * sw, a.y * sw);
        const int e1 = rowptr[row + 1];
        for (int e = rowptr[row]; e < e1; e++) {
            int s = csr_src[e];
            float w = csr_w[e];
            float2 hv = ld2v(h + (size_t)s * COLS + lane * 2);
            acc.x += w * hv.x; acc.y += w * hv.y;
        }
        st2v(z + (size_t)row * COLS + lane * 2, acc);
    }
}

// ---------------- fp32-compute tiled GEMM: C[M,256] = A[M,K] @ B[K,256] (+epilogues) ----------------
// MODE 0: C = A@B + bias
// MODE 1: C = relu(aggin*scale + shift) + A@B        (block-1 projection residual, fused BN epilogue)

template<typename TA, typename TC, int K, int MODE>
__global__ __launch_bounds__(256) void gemm_k(const TA* __restrict__ A, const float* __restrict__ B,
                                              const float* __restrict__ bias, TC* __restrict__ C,
                                              const float* __restrict__ scale, const float* __restrict__ shift,
                                              const TC* __restrict__ aggin, int M) {
    __shared__ float As[64][68];   // [m][k], +4 pad
    __shared__ float Bs[64][64];   // [k][n]
    const int tid = threadIdx.x;
    const int tx = tid & 15;
    const int ty = tid >> 4;
    const int rowBlock = blockIdx.x * 64;
    const int colBlock = blockIdx.y * 64;
    float acc[4][4] = {};

    for (int kt = 0; kt < K; kt += 64) {
#pragma unroll
        for (int i = 0; i < 4; i++) {
            int f = tid + i * 256;
            int r = f >> 4, kq = f & 15;
            int grow = rowBlock + r;
            float4 v = make_float4(0.f, 0.f, 0.f, 0.f);
            if (grow < M) v = ld4v(A + (size_t)grow * K + kt + kq * 4);
            *reinterpret_cast<float4*>(&As[r][kq * 4]) = v;
        }
#pragma unroll
        for (int i = 0; i < 4; i++) {
            int f = tid + i * 256;
            int kr = f >> 4, nq = f & 15;
            float4 v = *reinterpret_cast<const float4*>(B + (size_t)(kt + kr) * HD + colBlock + nq * 4);
            *reinterpret_cast<float4*>(&Bs[kr][nq * 4]) = v;
        }
        __syncthreads();
#pragma unroll
        for (int k = 0; k < 64; k++) {
            float4 b = *reinterpret_cast<const float4*>(&Bs[k][tx * 4]);
            float a0 = As[ty * 4 + 0][k];
            float a1 = As[ty * 4 + 1][k];
            float a2 = As[ty * 4 + 2][k];
            float a3 = As[ty * 4 + 3][k];
            acc[0][0] += a0 * b.x; acc[0][1] += a0 * b.y; acc[0][2] += a0 * b.z; acc[0][3] += a0 * b.w;
            acc[1][0] += a1 * b.x; acc[1][1] += a1 * b.y; acc[1][2] += a1 * b.z; acc[1][3] += a1 * b.w;
            acc[2][0] += a2 * b.x; acc[2][1] += a2 * b.y; acc[2][2] += a2 * b.z; acc[2][3] += a2 * b.w;
            acc[3][0] += a3 * b.x; acc[3][1] += a3 * b.y; acc[3][2] += a3 * b.z; acc[3][3] += a3 * b.w;
        }
        __syncthreads();
    }

#pragma unroll
    for (int mi = 0; mi < 4; mi++) {
        int r = rowBlock + ty * 4 + mi;
        if (r >= M) continue;
        int cbase = colBlock + tx * 4;
        float4 o;
        if (MODE == 0) {
            float4 bb = *reinterpret_cast<const float4*>(bias + cbase);
            o = make_float4(acc[mi][0] + bb.x, acc[mi][1] + bb.y, acc[mi][2] + bb.z, acc[mi][3] + bb.w);
        } else {
            float4 ag = ld4v(aggin + (size_t)r * HD + cbase);
            float4 sc = *reinterpret_cast<const float4*>(scale + cbase);
            float4 sh = *reinterpret_cast<const float4*>(shift + cbase);
            o.x = fmaxf(fmaf(ag.x, sc.x, sh.x), 0.f) + acc[mi][0];
            o.y = fmaxf(fmaf(ag.y, sc.y, sh.y), 0.f) + acc[mi][1];
            o.z = fmaxf(fmaf(ag.z, sc.z, sh.z), 0.f) + acc[mi][2];
            o.w = fmaxf(fmaf(ag.w, sc.w, sh.w), 0.f) + acc[mi][3];
        }
        st4v(C + (size_t)r * HD + cbase, o);
    }
}

// ---------------- BatchNorm ----------------

template<typename ST>
__global__ __launch_bounds__(256) void bn_stats_k(const ST* __restrict__ agg, float* __restrict__ sums) {
    const int c = threadIdx.x;
    const int rs = blockIdx.x * 196;
    const int re = min(rs + 196, NN);
    float s = 0.f, q = 0.f;
    for (int r = rs; r < re; r++) {
        float v = ld1(agg + (size_t)r * HD + c);
        s += v; q += v * v;
    }
    atomicAdd(&sums[c], s);
    atomicAdd(&sums[HD + c], q);
}

__global__ void bn_fin_k(const float* __restrict__ sums, const float* __restrict__ g,
                         const float* __restrict__ be, float* __restrict__ sc, float* __restrict__ sh) {
    int c = threadIdx.x;
    float m = sums[c] * (1.0f / NN);
    float v = sums[HD + c] * (1.0f / NN) - m * m;
    float s = g[c] * rsqrtf(v + BNEPS);
    sc[c] = s;
    sh[c] = be[c] - m * s;
}

template<typename ST>
__global__ __launch_bounds__(256) void epi_k(const ST* __restrict__ agg, const ST* __restrict__ res,
                                             const float* __restrict__ scp, const float* __restrict__ shp,
                                             ST* __restrict__ out) {
    const size_t total = (size_t)NN * (HD / 4);
    size_t i = (size_t)blockIdx.x * 256 + threadIdx.x;
    const size_t stride = (size_t)gridDim.x * 256;
    for (; i < total; i += stride) {
        int cq = ((int)(i & 63)) * 4;
        float4 a = ld4v(agg + i * 4);
        float4 r = ld4v(res + i * 4);
        float4 sc = *reinterpret_cast<const float4*>(scp + cq);
        float4 sh = *reinterpret_cast<const float4*>(shp + cq);
        float4 o;
        o.x = fmaxf(fmaf(a.x, sc.x, sh.x), 0.f) + r.x;
        o.y = fmaxf(fmaf(a.y, sc.y, sh.y), 0.f) + r.y;
        o.z = fmaxf(fmaf(a.z, sc.z, sh.z), 0.f) + r.z;
        o.w = fmaxf(fmaf(a.w, sc.w, sh.w), 0.f) + r.w;
        st4v(out + i * 4, o);
    }
}

// ---------------- pooling head ----------------

template<typename ST>
__global__ __launch_bounds__(256) void pool_sum_k(const ST* __restrict__ h, const int* __restrict__ batch,
                                                  float* __restrict__ pooled) {
    const int c = threadIdx.x;
    const int rs = blockIdx.x * 256;
    if (rs >= NN) return;
    const int re = min(rs + 256, NN);
    float acc = 0.f;
    int cur = batch[rs];
    for (int r = rs; r < re; r++) {
        int g = batch[r];
        if (g != cur) { atomicAdd(&pooled[(size_t)cur * HD + c], acc); acc = 0.f; cur = g; }
        acc += ld1(h + (size_t)r * HD + c);
    }
    atomicAdd(&pooled[(size_t)cur * HD + c], acc);
}

__global__ __launch_bounds__(256) void pool_cnt_k(const int* __restrict__ batch, int* __restrict__ gcnt) {
    int i = blockIdx.x * 256 + threadIdx.x;
    if (i < NN) atomicAdd(&gcnt[batch[i]], 1);
}

__global__ void pool_out_k(const float* __restrict__ pooled, const int* __restrict__ gcnt,
                           const float* __restrict__ Wl, const float* __restrict__ bl,
                           float* __restrict__ out) {
    int g = threadIdx.x;
    if (g < NG) {
        float s = 0.f;
        for (int c = 0; c < HD; c++) s += pooled[(size_t)g * HD + c] * Wl[c];
        float cn = fmaxf((float)gcnt[g], 1.0f);
        out[g] = s / cn + bl[0];
    }
}

// ---------------- launcher ----------------

static inline size_t alignup(size_t x) { return (x + 255) & ~size_t(255); }

template<typename ST>
static void pipeline(void* const* d_in, void* d_out, void* d_ws, hipStream_t stream) {
    const float* x    = (const float*)d_in[0];
    const int*   ei   = (const int*)d_in[1];
    const int*   bat  = (const int*)d_in[2];
    const float* W1   = (const float*)d_in[3];
    const float* bi1  = (const float*)d_in[4];
    const float* g1   = (const float*)d_in[5];
    const float* be1  = (const float*)d_in[6];
    const float* P1   = (const float*)d_in[7];
    const float* W2   = (const float*)d_in[8];
    const float* bi2  = (const float*)d_in[9];
    const float* g2   = (const float*)d_in[10];
    const float* be2  = (const float*)d_in[11];
    const float* W3   = (const float*)d_in[12];
    const float* bi3  = (const float*)d_in[13];
    const float* g3   = (const float*)d_in[14];
    const float* be3  = (const float*)d_in[15];
    const float* W4   = (const float*)d_in[16];
    const float* bi4  = (const float*)d_in[17];
    const float* g4   = (const float*)d_in[18];
    const float* be4  = (const float*)d_in[19];
    const float* Wl   = (const float*)d_in[20];
    const float* bl   = (const float*)d_in[21];
    float* out = (float*)d_out;

    const int* e_src = ei;
    const int* e_dst = ei + NE;

    char* p = (char*)d_ws;
    auto alloc = [&](size_t bytes) { char* q = p; p += alignup(bytes); return q; };
    ST*    fb0     = (ST*)alloc((size_t)NN * HD * sizeof(ST));
    ST*    fb1     = (ST*)alloc((size_t)NN * HD * sizeof(ST));
    ST*    fb2     = (ST*)alloc((size_t)NN * HD * sizeof(ST));
    int*   cnt     = (int*)alloc((size_t)NN * 4);
    int*   cursor  = (int*)alloc((size_t)NN * 4);
    float* dis     = (float*)alloc((size_t)NN * 4);
    float* selfw   = (float*)alloc((size_t)NN * 4);
    int*   rowptr  = (int*)alloc((size_t)(NN + 1) * 4);
    int*   csr_src = (int*)alloc((size_t)NE * 4);
    float* csr_w   = (float*)alloc((size_t)NE * 4);
    int*   partials= (int*)alloc(128 * 4);
    float* sums    = (float*)alloc(2 * HD * 4);
    float* bnsc    = (float*)alloc(HD * 4);
    float* bnsh    = (float*)alloc(HD * 4);
    float* pooled  = (float*)alloc((size_t)NG * HD * 4);
    int*   gcnt    = (int*)alloc(NG * 4);

    const int NB = (NN + 1023) / 1024;  // 98

    // ---- graph preprocessing ----
    hipMemsetAsync(cnt, 0, (size_t)NN * 4, stream);
    hipMemsetAsync(cursor, 0, (size_t)NN * 4, stream);
    count_deg_k<<<(NE + 255) / 256, 256, 0, stream>>>(e_dst, cnt);
    node_prep_k<<<(NN + 255) / 256, 256, 0, stream>>>(cnt, dis, selfw);
    scan_reduce_k<<<NB, 1024, 0, stream>>>(cnt, partials);
    scan_partials_k<<<1, 64, 0, stream>>>(partials, NB);
    scan_write_k<<<NB, 1024, 0, stream>>>(cnt, partials, rowptr);
    fill_csr_k<<<(NE + 255) / 256, 256, 0, stream>>>(e_src, e_dst, rowptr, cursor, dis, csr_src, csr_w);

    dim3 ggrid(1563, 4, 1);

    // ---- block 1 (x:128 -> 256, projection residual) ----
    spmm_k<float, ST, 128><<<NN / 4, 256, 0, stream>>>(x, rowptr, csr_src, csr_w, selfw, fb0);
    gemm_k<ST, ST, 128, 0><<<ggrid, 256, 0, stream>>>(fb0, W1, bi1, fb2, nullptr, nullptr, (const ST*)nullptr, NN);
    hipMemsetAsync(sums, 0, 2 * HD * 4, stream);
    bn_stats_k<ST><<<511, 256, 0, stream>>>(fb2, sums);
    bn_fin_k<<<1, 256, 0, stream>>>(sums, g1, be1, bnsc, bnsh);
    gemm_k<float, ST, 128, 1><<<ggrid, 256, 0, stream>>>(x, P1, nullptr, fb1, bnsc, bnsh, fb2, NN);
    // h1 = fb1

    // ---- block 2 ----
    spmm_k<ST, ST, 256><<<NN / 4, 256, 0, stream>>>(fb1, rowptr, csr_src, csr_w, selfw, fb0);
    gemm_k<ST, ST, 256, 0><<<ggrid, 256, 0, stream>>>(fb0, W2, bi2, fb2, nullptr, nullptr, (const ST*)nullptr, NN);
    hipMemsetAsync(sums, 0, 2 * HD * 4, stream);
    bn_stats_k<ST><<<511, 256, 0, stream>>>(fb2, sums);
    bn_fin_k<<<1, 256, 0, stream>>>(sums, g2, be2, bnsc, bnsh);
    epi_k<ST><<<4096, 256, 0, stream>>>(fb2, fb1, bnsc, bnsh, fb0);
    // h2 = fb0

    // ---- block 3 ----
    spmm_k<ST, ST, 256><<<NN / 4, 256, 0, stream>>>(fb0, rowptr, csr_src, csr_w, selfw, fb1);
    gemm_k<ST, ST, 256, 0><<<ggrid, 256, 0, stream>>>(fb1, W3, bi3, fb2, nullptr, nullptr, (const ST*)nullptr, NN);
    hipMemsetAsync(sums, 0, 2 * HD * 4, stream);
    bn_stats_k<ST><<<511, 256, 0, stream>>>(fb2, sums);
    bn_fin_k<<<1, 256, 0, stream>>>(sums, g3, be3, bnsc, bnsh);
    epi_k<ST><<<4096, 256, 0, stream>>>(fb2, fb0, bnsc, bnsh, fb1);
    // h3 = fb1

    // ---- block 4 ----
    spmm_k<ST, ST, 256><<<NN / 4, 256, 0, stream>>>(fb1, rowptr, csr_src, csr_w, selfw, fb0);
    gemm_k<ST, ST, 256, 0><<<ggrid, 256, 0, stream>>>(fb0, W4, bi4, fb2, nullptr, nullptr, (const ST*)nullptr, NN);
    hipMemsetAsync(sums, 0, 2 * HD * 4, stream);
    bn_stats_k<ST><<<511, 256, 0, stream>>>(fb2, sums);
    bn_fin_k<<<1, 256, 0, stream>>>(sums, g4, be4, bnsc, bnsh);
    epi_k<ST><<<4096, 256, 0, stream>>>(fb2, fb1, bnsc, bnsh, fb0);
    // h4 = fb0

    // ---- pooling head ----
    hipMemsetAsync(pooled, 0, (size_t)NG * HD * 4, stream);
    hipMemsetAsync(gcnt, 0, NG * 4, stream);
    pool_sum_k<ST><<<(NN + 255) / 256, 256, 0, stream>>>(fb0, bat, pooled);
    pool_cnt_k<<<(NN + 255) / 256, 256, 0, stream>>>(bat, gcnt);
    pool_out_k<<<1, 64, 0, stream>>>(pooled, gcnt, Wl, bl, out);
}

extern "C" void kernel_launch(void* const* d_in, const int* in_sizes, int n_in,
                              void* d_out, int out_size, void* d_ws, size_t ws_size,
                              hipStream_t stream) {
    // fp32 pipeline needs ~318 MB of workspace; bf16-storage pipeline ~158 MB.
    // Choose based on the (fixed) ws_size so we never overflow d_ws.
    if (ws_size >= 340000000ull) {
        pipeline<float>(d_in, d_out, d_ws, stream);
    } else {
        pipeline<unsigned short>(d_in, d_out, d_ws, stream);
    }
}

// Round 3
// 1747.064 us; speedup vs baseline: 1.2840x; 1.2840x over previous
//
#include <hip/hip_runtime.h>
#include <cstdint>
#include <cstddef>

#define NN 100000
#define NE 1000000
#define FIN 128
#define HD 256
#define NG 64
#define BNEPS 1e-5f

// ---------- bf16<->f32 helpers (storage type ST is float or ushort[bf16]) ----------

__device__ inline float b2f(unsigned short u) {
    union { float f; unsigned int i; } x; x.i = ((unsigned int)u) << 16; return x.f;
}
__device__ inline unsigned short f2b(float f) {
    union { float f; unsigned int i; } x; x.f = f;
    unsigned int r = x.i + 0x7FFFu + ((x.i >> 16) & 1u);
    return (unsigned short)(r >> 16);
}
__device__ inline float  ld1(const float* p) { return *p; }
__device__ inline float  ld1(const unsigned short* p) { return b2f(*p); }
__device__ inline float4 ld4v(const float* p) { return *(const float4*)p; }
__device__ inline float4 ld4v(const unsigned short* p) {
    ushort4 u = *(const ushort4*)p;
    return make_float4(b2f(u.x), b2f(u.y), b2f(u.z), b2f(u.w));
}
__device__ inline float2 ld2v(const float* p) { return *(const float2*)p; }
__device__ inline float2 ld2v(const unsigned short* p) {
    ushort2 u = *(const ushort2*)p;
    return make_float2(b2f(u.x), b2f(u.y));
}
__device__ inline void st4v(float* p, float4 v) { *(float4*)p = v; }
__device__ inline void st4v(unsigned short* p, float4 v) {
    ushort4 u; u.x = f2b(v.x); u.y = f2b(v.y); u.z = f2b(v.z); u.w = f2b(v.w);
    *(ushort4*)p = u;
}
__device__ inline void st2v(float* p, float2 v) { *(float2*)p = v; }
__device__ inline void st2v(unsigned short* p, float2 v) {
    ushort2 u; u.x = f2b(v.x); u.y = f2b(v.y);
    *(ushort2*)p = u;
}

// ---------------- graph preprocessing ----------------

__global__ __launch_bounds__(256) void count_deg_k(const int* __restrict__ dst, int* __restrict__ cnt) {
    int e = blockIdx.x * 256 + threadIdx.x;
    if (e < NE) atomicAdd(&cnt[dst[e]], 1);
}

__global__ __launch_bounds__(256) void node_prep_k(const int* __restrict__ cnt,
                                                   float* __restrict__ dis, float* __restrict__ selfw) {
    int i = blockIdx.x * 256 + threadIdx.x;
    if (i < NN) {
        float d = (float)cnt[i] + 1.0f;
        dis[i] = rsqrtf(d);
        selfw[i] = 1.0f / d;
    }
}

__global__ __launch_bounds__(1024) void scan_reduce_k(const int* __restrict__ cnt, int* __restrict__ partials) {
    __shared__ int sh[1024];
    int i = blockIdx.x * 1024 + threadIdx.x;
    sh[threadIdx.x] = (i < NN) ? cnt[i] : 0;
    __syncthreads();
    for (int off = 512; off > 0; off >>= 1) {
        if (threadIdx.x < off) sh[threadIdx.x] += sh[threadIdx.x + off];
        __syncthreads();
    }
    if (threadIdx.x == 0) partials[blockIdx.x] = sh[0];
}

__global__ void scan_partials_k(int* partials, int nb) {
    if (threadIdx.x == 0 && blockIdx.x == 0) {
        int run = 0;
        for (int b = 0; b < nb; b++) { int v = partials[b]; partials[b] = run; run += v; }
    }
}

__global__ __launch_bounds__(1024) void scan_write_k(const int* __restrict__ cnt,
                                                     const int* __restrict__ partials,
                                                     int* __restrict__ rowptr) {
    __shared__ int sh[1024];
    int i = blockIdx.x * 1024 + threadIdx.x;
    int v = (i < NN) ? cnt[i] : 0;
    sh[threadIdx.x] = v;
    __syncthreads();
    for (int off = 1; off < 1024; off <<= 1) {
        int t = (threadIdx.x >= off) ? sh[threadIdx.x - off] : 0;
        __syncthreads();
        sh[threadIdx.x] += t;
        __syncthreads();
    }
    if (i < NN) rowptr[i] = partials[blockIdx.x] + sh[threadIdx.x] - v;
    if (i == NN - 1) rowptr[NN] = partials[blockIdx.x] + sh[threadIdx.x];
}

__global__ __launch_bounds__(256) void fill_csr_k(const int* __restrict__ src, const int* __restrict__ dst,
                                                  const int* __restrict__ rowptr, int* __restrict__ cursor,
                                                  const float* __restrict__ dis,
                                                  int* __restrict__ csr_src, float* __restrict__ csr_w) {
    int e = blockIdx.x * 256 + threadIdx.x;
    if (e < NE) {
        int d = dst[e], s = src[e];
        int pos = rowptr[d] + atomicAdd(&cursor[d], 1);
        csr_src[pos] = s;
        csr_w[pos] = dis[s] * dis[d];
    }
}

// ---------------- SpMM: z[i,:] = selfw[i]*h[i,:] + sum_e w_e * h[src_e,:] ----------------

template<typename SIN, typename SOUT, int COLS>
__global__ __launch_bounds__(256) void spmm_k(const SIN* __restrict__ h,
                                              const int* __restrict__ rowptr,
                                              const int* __restrict__ csr_src,
                                              const float* __restrict__ csr_w,
                                              const float* __restrict__ selfw,
                                              SOUT* __restrict__ z) {
    const int lane = threadIdx.x & 63;
    const int row = blockIdx.x * 4 + (threadIdx.x >> 6);
    if (row >= NN) return;
    if constexpr (COLS == 256) {
        float4 a = ld4v(h + (size_t)row * COLS + lane * 4);
        float sw = selfw[row];
        float4 acc = make_float4(a.x * sw, a.y * sw, a.z * sw, a.w * sw);
        const int e1 = rowptr[row + 1];
        for (int e = rowptr[row]; e < e1; e++) {
            int s = csr_src[e];
            float w = csr_w[e];
            float4 hv = ld4v(h + (size_t)s * COLS + lane * 4);
            acc.x += w * hv.x; acc.y += w * hv.y; acc.z += w * hv.z; acc.w += w * hv.w;
        }
        st4v(z + (size_t)row * COLS + lane * 4, acc);
    } else {
        float2 a = ld2v(h + (size_t)row * COLS + lane * 2);
        float sw = selfw[row];
        float2 acc = make_float2(a.x * sw, a.y * sw);
        const int e1 = rowptr[row + 1];
        for (int e = rowptr[row]; e < e1; e++) {
            int s = csr_src[e];
            float w = csr_w[e];
            float2 hv = ld2v(h + (size_t)s * COLS + lane * 2);
            acc.x += w * hv.x; acc.y += w * hv.y;
        }
        st2v(z + (size_t)row * COLS + lane * 2, acc);
    }
}

// ---------------- fp32-compute tiled GEMM: C[M,256] = A[M,K] @ B[K,256] (+epilogues) ----------------
// MODE 0: C = A@B + bias
// MODE 1: C = relu(aggin*scale + shift) + A@B        (block-1 projection residual, fused BN epilogue)

template<typename TA, typename TC, int K, int MODE>
__global__ __launch_bounds__(256) void gemm_k(const TA* __restrict__ A, const float* __restrict__ B,
                                              const float* __restrict__ bias, TC* __restrict__ C,
                                              const float* __restrict__ scale, const float* __restrict__ shift,
                                              const TC* __restrict__ aggin, int M) {
    __shared__ float As[64][68];   // [m][k], +4 pad
    __shared__ float Bs[64][64];   // [k][n]
    const int tid = threadIdx.x;
    const int tx = tid & 15;
    const int ty = tid >> 4;
    const int rowBlock = blockIdx.x * 64;
    const int colBlock = blockIdx.y * 64;
    float acc[4][4] = {};

    for (int kt = 0; kt < K; kt += 64) {
#pragma unroll
        for (int i = 0; i < 4; i++) {
            int f = tid + i * 256;
            int r = f >> 4, kq = f & 15;
            int grow = rowBlock + r;
            float4 v = make_float4(0.f, 0.f, 0.f, 0.f);
            if (grow < M) v = ld4v(A + (size_t)grow * K + kt + kq * 4);
            *reinterpret_cast<float4*>(&As[r][kq * 4]) = v;
        }
#pragma unroll
        for (int i = 0; i < 4; i++) {
            int f = tid + i * 256;
            int kr = f >> 4, nq = f & 15;
            float4 v = *reinterpret_cast<const float4*>(B + (size_t)(kt + kr) * HD + colBlock + nq * 4);
            *reinterpret_cast<float4*>(&Bs[kr][nq * 4]) = v;
        }
        __syncthreads();
#pragma unroll
        for (int k = 0; k < 64; k++) {
            float4 b = *reinterpret_cast<const float4*>(&Bs[k][tx * 4]);
            float a0 = As[ty * 4 + 0][k];
            float a1 = As[ty * 4 + 1][k];
            float a2 = As[ty * 4 + 2][k];
            float a3 = As[ty * 4 + 3][k];
            acc[0][0] += a0 * b.x; acc[0][1] += a0 * b.y; acc[0][2] += a0 * b.z; acc[0][3] += a0 * b.w;
            acc[1][0] += a1 * b.x; acc[1][1] += a1 * b.y; acc[1][2] += a1 * b.z; acc[1][3] += a1 * b.w;
            acc[2][0] += a2 * b.x; acc[2][1] += a2 * b.y; acc[2][2] += a2 * b.z; acc[2][3] += a2 * b.w;
            acc[3][0] += a3 * b.x; acc[3][1] += a3 * b.y; acc[3][2] += a3 * b.z; acc[3][3] += a3 * b.w;
        }
        __syncthreads();
    }

#pragma unroll
    for (int mi = 0; mi < 4; mi++) {
        int r = rowBlock + ty * 4 + mi;
        if (r >= M) continue;
        int cbase = colBlock + tx * 4;
        float4 o;
        if (MODE == 0) {
            float4 bb = *reinterpret_cast<const float4*>(bias + cbase);
            o = make_float4(acc[mi][0] + bb.x, acc[mi][1] + bb.y, acc[mi][2] + bb.z, acc[mi][3] + bb.w);
        } else {
            float4 ag = ld4v(aggin + (size_t)r * HD + cbase);
            float4 sc = *reinterpret_cast<const float4*>(scale + cbase);
            float4 sh = *reinterpret_cast<const float4*>(shift + cbase);
            o.x = fmaxf(fmaf(ag.x, sc.x, sh.x), 0.f) + acc[mi][0];
            o.y = fmaxf(fmaf(ag.y, sc.y, sh.y), 0.f) + acc[mi][1];
            o.z = fmaxf(fmaf(ag.z, sc.z, sh.z), 0.f) + acc[mi][2];
            o.w = fmaxf(fmaf(ag.w, sc.w, sh.w), 0.f) + acc[mi][3];
        }
        st4v(C + (size_t)r * HD + cbase, o);
    }
}

// ---------------- BatchNorm ----------------

template<typename ST>
__global__ __launch_bounds__(256) void bn_stats_k(const ST* __restrict__ agg, float* __restrict__ sums) {
    const int c = threadIdx.x;
    const int rs = blockIdx.x * 196;
    const int re = min(rs + 196, NN);
    float s = 0.f, q = 0.f;
    for (int r = rs; r < re; r++) {
        float v = ld1(agg + (size_t)r * HD + c);
        s += v; q += v * v;
    }
    atomicAdd(&sums[c], s);
    atomicAdd(&sums[HD + c], q);
}

__global__ void bn_fin_k(const float* __restrict__ sums, const float* __restrict__ g,
                         const float* __restrict__ be, float* __restrict__ sc, float* __restrict__ sh) {
    int c = threadIdx.x;
    float m = sums[c] * (1.0f / NN);
    float v = sums[HD + c] * (1.0f / NN) - m * m;
    float s = g[c] * rsqrtf(v + BNEPS);
    sc[c] = s;
    sh[c] = be[c] - m * s;
}

template<typename ST>
__global__ __launch_bounds__(256) void epi_k(const ST* __restrict__ agg, const ST* __restrict__ res,
                                             const float* __restrict__ scp, const float* __restrict__ shp,
                                             ST* __restrict__ out) {
    const size_t total = (size_t)NN * (HD / 4);
    size_t i = (size_t)blockIdx.x * 256 + threadIdx.x;
    const size_t stride = (size_t)gridDim.x * 256;
    for (; i < total; i += stride) {
        int cq = ((int)(i & 63)) * 4;
        float4 a = ld4v(agg + i * 4);
        float4 r = ld4v(res + i * 4);
        float4 sc = *reinterpret_cast<const float4*>(scp + cq);
        float4 sh = *reinterpret_cast<const float4*>(shp + cq);
        float4 o;
        o.x = fmaxf(fmaf(a.x, sc.x, sh.x), 0.f) + r.x;
        o.y = fmaxf(fmaf(a.y, sc.y, sh.y), 0.f) + r.y;
        o.z = fmaxf(fmaf(a.z, sc.z, sh.z), 0.f) + r.z;
        o.w = fmaxf(fmaf(a.w, sc.w, sh.w), 0.f) + r.w;
        st4v(out + i * 4, o);
    }
}

// ---------------- pooling head ----------------

template<typename ST>
__global__ __launch_bounds__(256) void pool_sum_k(const ST* __restrict__ h, const int* __restrict__ batch,
                                                  float* __restrict__ pooled) {
    const int c = threadIdx.x;
    const int rs = blockIdx.x * 256;
    if (rs >= NN) return;
    const int re = min(rs + 256, NN);
    float acc = 0.f;
    int cur = batch[rs];
    for (int r = rs; r < re; r++) {
        int g = batch[r];
        if (g != cur) { atomicAdd(&pooled[(size_t)cur * HD + c], acc); acc = 0.f; cur = g; }
        acc += ld1(h + (size_t)r * HD + c);
    }
    atomicAdd(&pooled[(size_t)cur * HD + c], acc);
}

// counts come from binary search on the SORTED batch array — no atomics.
__global__ void pool_out_k(const float* __restrict__ pooled, const int* __restrict__ batch,
                           const float* __restrict__ Wl, const float* __restrict__ bl,
                           float* __restrict__ out) {
    int g = threadIdx.x;
    if (g < NG) {
        auto lb = [&](int val) {
            int lo = 0, hi = NN;
            while (lo < hi) { int mid = (lo + hi) >> 1; if (batch[mid] < val) lo = mid + 1; else hi = mid; }
            return lo;
        };
        int c0 = lb(g), c1 = lb(g + 1);
        float cn = fmaxf((float)(c1 - c0), 1.0f);
        float s = 0.f;
        for (int c = 0; c < HD; c++) s += pooled[(size_t)g * HD + c] * Wl[c];
        out[g] = s / cn + bl[0];
    }
}

// ---------------- launcher ----------------

static inline size_t alignup(size_t x) { return (x + 255) & ~size_t(255); }

template<typename ST>
static void pipeline(void* const* d_in, void* d_out, void* d_ws, hipStream_t stream) {
    const float* x    = (const float*)d_in[0];
    const int*   ei   = (const int*)d_in[1];
    const int*   bat  = (const int*)d_in[2];
    const float* W1   = (const float*)d_in[3];
    const float* bi1  = (const float*)d_in[4];
    const float* g1   = (const float*)d_in[5];
    const float* be1  = (const float*)d_in[6];
    const float* P1   = (const float*)d_in[7];
    const float* W2   = (const float*)d_in[8];
    const float* bi2  = (const float*)d_in[9];
    const float* g2   = (const float*)d_in[10];
    const float* be2  = (const float*)d_in[11];
    const float* W3   = (const float*)d_in[12];
    const float* bi3  = (const float*)d_in[13];
    const float* g3   = (const float*)d_in[14];
    const float* be3  = (const float*)d_in[15];
    const float* W4   = (const float*)d_in[16];
    const float* bi4  = (const float*)d_in[17];
    const float* g4   = (const float*)d_in[18];
    const float* be4  = (const float*)d_in[19];
    const float* Wl   = (const float*)d_in[20];
    const float* bl   = (const float*)d_in[21];
    float* out = (float*)d_out;

    const int* e_src = ei;
    const int* e_dst = ei + NE;

    char* p = (char*)d_ws;
    auto alloc = [&](size_t bytes) { char* q = p; p += alignup(bytes); return q; };
    ST*    fb0     = (ST*)alloc((size_t)NN * HD * sizeof(ST));
    ST*    fb1     = (ST*)alloc((size_t)NN * HD * sizeof(ST));
    ST*    fb2     = (ST*)alloc((size_t)NN * HD * sizeof(ST));
    int*   cnt     = (int*)alloc((size_t)NN * 4);
    int*   cursor  = (int*)alloc((size_t)NN * 4);
    float* dis     = (float*)alloc((size_t)NN * 4);
    float* selfw   = (float*)alloc((size_t)NN * 4);
    int*   rowptr  = (int*)alloc((size_t)(NN + 1) * 4);
    int*   csr_src = (int*)alloc((size_t)NE * 4);
    float* csr_w   = (float*)alloc((size_t)NE * 4);
    int*   partials= (int*)alloc(128 * 4);
    float* sums    = (float*)alloc(2 * HD * 4);
    float* bnsc    = (float*)alloc(HD * 4);
    float* bnsh    = (float*)alloc(HD * 4);
    float* pooled  = (float*)alloc((size_t)NG * HD * 4);

    const int NB = (NN + 1023) / 1024;  // 98

    // ---- graph preprocessing ----
    hipMemsetAsync(cnt, 0, (size_t)NN * 4, stream);
    hipMemsetAsync(cursor, 0, (size_t)NN * 4, stream);
    count_deg_k<<<(NE + 255) / 256, 256, 0, stream>>>(e_dst, cnt);
    node_prep_k<<<(NN + 255) / 256, 256, 0, stream>>>(cnt, dis, selfw);
    scan_reduce_k<<<NB, 1024, 0, stream>>>(cnt, partials);
    scan_partials_k<<<1, 64, 0, stream>>>(partials, NB);
    scan_write_k<<<NB, 1024, 0, stream>>>(cnt, partials, rowptr);
    fill_csr_k<<<(NE + 255) / 256, 256, 0, stream>>>(e_src, e_dst, rowptr, cursor, dis, csr_src, csr_w);

    dim3 ggrid(1563, 4, 1);

    // ---- block 1 (x:128 -> 256, projection residual) ----
    spmm_k<float, ST, 128><<<NN / 4, 256, 0, stream>>>(x, rowptr, csr_src, csr_w, selfw, fb0);
    gemm_k<ST, ST, 128, 0><<<ggrid, 256, 0, stream>>>(fb0, W1, bi1, fb2, nullptr, nullptr, (const ST*)nullptr, NN);
    hipMemsetAsync(sums, 0, 2 * HD * 4, stream);
    bn_stats_k<ST><<<511, 256, 0, stream>>>(fb2, sums);
    bn_fin_k<<<1, 256, 0, stream>>>(sums, g1, be1, bnsc, bnsh);
    gemm_k<float, ST, 128, 1><<<ggrid, 256, 0, stream>>>(x, P1, nullptr, fb1, bnsc, bnsh, fb2, NN);
    // h1 = fb1

    // ---- block 2 ----
    spmm_k<ST, ST, 256><<<NN / 4, 256, 0, stream>>>(fb1, rowptr, csr_src, csr_w, selfw, fb0);
    gemm_k<ST, ST, 256, 0><<<ggrid, 256, 0, stream>>>(fb0, W2, bi2, fb2, nullptr, nullptr, (const ST*)nullptr, NN);
    hipMemsetAsync(sums, 0, 2 * HD * 4, stream);
    bn_stats_k<ST><<<511, 256, 0, stream>>>(fb2, sums);
    bn_fin_k<<<1, 256, 0, stream>>>(sums, g2, be2, bnsc, bnsh);
    epi_k<ST><<<4096, 256, 0, stream>>>(fb2, fb1, bnsc, bnsh, fb0);
    // h2 = fb0

    // ---- block 3 ----
    spmm_k<ST, ST, 256><<<NN / 4, 256, 0, stream>>>(fb0, rowptr, csr_src, csr_w, selfw, fb1);
    gemm_k<ST, ST, 256, 0><<<ggrid, 256, 0, stream>>>(fb1, W3, bi3, fb2, nullptr, nullptr, (const ST*)nullptr, NN);
    hipMemsetAsync(sums, 0, 2 * HD * 4, stream);
    bn_stats_k<ST><<<511, 256, 0, stream>>>(fb2, sums);
    bn_fin_k<<<1, 256, 0, stream>>>(sums, g3, be3, bnsc, bnsh);
    epi_k<ST><<<4096, 256, 0, stream>>>(fb2, fb0, bnsc, bnsh, fb1);
    // h3 = fb1

    // ---- block 4 ----
    spmm_k<ST, ST, 256><<<NN / 4, 256, 0, stream>>>(fb1, rowptr, csr_src, csr_w, selfw, fb0);
    gemm_k<ST, ST, 256, 0><<<ggrid, 256, 0, stream>>>(fb0, W4, bi4, fb2, nullptr, nullptr, (const ST*)nullptr, NN);
    hipMemsetAsync(sums, 0, 2 * HD * 4, stream);
    bn_stats_k<ST><<<511, 256, 0, stream>>>(fb2, sums);
    bn_fin_k<<<1, 256, 0, stream>>>(sums, g4, be4, bnsc, bnsh);
    epi_k<ST><<<4096, 256, 0, stream>>>(fb2, fb1, bnsc, bnsh, fb0);
    // h4 = fb0

    // ---- pooling head ----
    hipMemsetAsync(pooled, 0, (size_t)NG * HD * 4, stream);
    pool_sum_k<ST><<<(NN + 255) / 256, 256, 0, stream>>>(fb0, bat, pooled);
    pool_out_k<<<1, 64, 0, stream>>>(pooled, bat, Wl, bl, out);
}

extern "C" void kernel_launch(void* const* d_in, const int* in_sizes, int n_in,
                              void* d_out, int out_size, void* d_ws, size_t ws_size,
                              hipStream_t stream) {
    // fp32 pipeline needs ~318 MB of workspace; bf16-storage pipeline ~158 MB.
    // Choose based on the (fixed) ws_size so we never overflow d_ws.
    if (ws_size >= 340000000ull) {
        pipeline<float>(d_in, d_out, d_ws, stream);
    } else {
        pipeline<unsigned short>(d_in, d_out, d_ws, stream);
    }
}

// Round 4
// 1208.612 us; speedup vs baseline: 1.8560x; 1.4455x over previous
//
#include <hip/hip_runtime.h>
#include <cstdint>
#include <cstddef>

#define NN 100000
#define NE 1000000
#define FIN 128
#define HD 256
#define NG 64
#define BNEPS 1e-5f

typedef unsigned short ushort_t;
typedef __attribute__((ext_vector_type(8))) short bf16x8;
typedef __attribute__((ext_vector_type(4))) float f32x4;

// ---------- bf16<->f32 helpers (storage is raw bf16 bits in ushort) ----------

__device__ inline float b2f(unsigned short u) {
    union { float f; unsigned int i; } x; x.i = ((unsigned int)u) << 16; return x.f;
}
__device__ inline unsigned short f2b(float f) {
    union { float f; unsigned int i; } x; x.f = f;
    unsigned int r = x.i + 0x7FFFu + ((x.i >> 16) & 1u);
    return (unsigned short)(r >> 16);
}
__device__ inline float  ld1(const unsigned short* p) { return b2f(*p); }
__device__ inline float4 ld4v(const unsigned short* p) {
    ushort4 u = *(const ushort4*)p;
    return make_float4(b2f(u.x), b2f(u.y), b2f(u.z), b2f(u.w));
}
__device__ inline float2 ld2v(const float* p) { return *(const float2*)p; }
__device__ inline float2 ld2v(const unsigned short* p) {
    ushort2 u = *(const ushort2*)p;
    return make_float2(b2f(u.x), b2f(u.y));
}
__device__ inline void st4v(unsigned short* p, float4 v) {
    ushort4 u; u.x = f2b(v.x); u.y = f2b(v.y); u.z = f2b(v.z); u.w = f2b(v.w);
    *(ushort4*)p = u;
}
__device__ inline void st2v(unsigned short* p, float2 v) {
    ushort2 u; u.x = f2b(v.x); u.y = f2b(v.y);
    *(ushort2*)p = u;
}

// ---------------- graph preprocessing ----------------

__global__ __launch_bounds__(256) void count_deg_k(const int* __restrict__ dst, int* __restrict__ cnt) {
    int e = blockIdx.x * 256 + threadIdx.x;
    if (e < NE) atomicAdd(&cnt[dst[e]], 1);
}

__global__ __launch_bounds__(256) void node_prep_k(const int* __restrict__ cnt,
                                                   float* __restrict__ dis, float* __restrict__ selfw) {
    int i = blockIdx.x * 256 + threadIdx.x;
    if (i < NN) {
        float d = (float)cnt[i] + 1.0f;
        dis[i] = rsqrtf(d);
        selfw[i] = 1.0f / d;
    }
}

__global__ __launch_bounds__(1024) void scan_reduce_k(const int* __restrict__ cnt, int* __restrict__ partials) {
    __shared__ int sh[1024];
    int i = blockIdx.x * 1024 + threadIdx.x;
    sh[threadIdx.x] = (i < NN) ? cnt[i] : 0;
    __syncthreads();
    for (int off = 512; off > 0; off >>= 1) {
        if (threadIdx.x < off) sh[threadIdx.x] += sh[threadIdx.x + off];
        __syncthreads();
    }
    if (threadIdx.x == 0) partials[blockIdx.x] = sh[0];
}

__global__ void scan_partials_k(int* partials, int nb) {
    if (threadIdx.x == 0 && blockIdx.x == 0) {
        int run = 0;
        for (int b = 0; b < nb; b++) { int v = partials[b]; partials[b] = run; run += v; }
    }
}

__global__ __launch_bounds__(1024) void scan_write_k(const int* __restrict__ cnt,
                                                     const int* __restrict__ partials,
                                                     int* __restrict__ rowptr) {
    __shared__ int sh[1024];
    int i = blockIdx.x * 1024 + threadIdx.x;
    int v = (i < NN) ? cnt[i] : 0;
    sh[threadIdx.x] = v;
    __syncthreads();
    for (int off = 1; off < 1024; off <<= 1) {
        int t = (threadIdx.x >= off) ? sh[threadIdx.x - off] : 0;
        __syncthreads();
        sh[threadIdx.x] += t;
        __syncthreads();
    }
    if (i < NN) rowptr[i] = partials[blockIdx.x] + sh[threadIdx.x] - v;
    if (i == NN - 1) rowptr[NN] = partials[blockIdx.x] + sh[threadIdx.x];
}

__global__ __launch_bounds__(256) void fill_csr_k(const int* __restrict__ src, const int* __restrict__ dst,
                                                  const int* __restrict__ rowptr, int* __restrict__ cursor,
                                                  const float* __restrict__ dis,
                                                  int* __restrict__ csr_src, float* __restrict__ csr_w) {
    int e = blockIdx.x * 256 + threadIdx.x;
    if (e < NE) {
        int d = dst[e], s = src[e];
        int pos = rowptr[d] + atomicAdd(&cursor[d], 1);
        csr_src[pos] = s;
        csr_w[pos] = dis[s] * dis[d];
    }
}

// ---- weight prep: W[K][256] fp32 -> Bt[256][K] bf16 (pre-transposed, N-major) ----
__global__ __launch_bounds__(256) void wt_k(const float* __restrict__ W, unsigned short* __restrict__ Bt, int K) {
    int i = blockIdx.x * 256 + threadIdx.x;
    if (i < K * 256) {
        int k = i >> 8, n = i & 255;
        Bt[n * K + k] = f2b(W[k * 256 + n]);
    }
}

// ---------------- SpMM: z[i,:] = selfw[i]*h[i,:] + sum_e w_e * h[src_e,:] ----------------

template<typename SIN, int COLS>
__global__ __launch_bounds__(256) void spmm_k(const SIN* __restrict__ h,
                                              const int* __restrict__ rowptr,
                                              const int* __restrict__ csr_src,
                                              const float* __restrict__ csr_w,
                                              const float* __restrict__ selfw,
                                              unsigned short* __restrict__ z) {
    const int lane = threadIdx.x & 63;
    const int row = blockIdx.x * 4 + (threadIdx.x >> 6);
    if (row >= NN) return;
    if constexpr (COLS == 256) {
        float4 a = ld4v(h + (size_t)row * COLS + lane * 4);
        float sw = selfw[row];
        float4 acc = make_float4(a.x * sw, a.y * sw, a.z * sw, a.w * sw);
        const int e1 = rowptr[row + 1];
        for (int e = rowptr[row]; e < e1; e++) {
            int s = csr_src[e];
            float w = csr_w[e];
            float4 hv = ld4v(h + (size_t)s * COLS + lane * 4);
            acc.x += w * hv.x; acc.y += w * hv.y; acc.z += w * hv.z; acc.w += w * hv.w;
        }
        st4v(z + (size_t)row * COLS + lane * 4, acc);
    } else {
        float2 a = ld2v(h + (size_t)row * COLS + lane * 2);
        float sw = selfw[row];
        float2 acc = make_float2(a.x * sw, a.y * sw);
        const int e1 = rowptr[row + 1];
        for (int e = rowptr[row]; e < e1; e++) {
            int s = csr_src[e];
            float w = csr_w[e];
            float2 hv = ld2v(h + (size_t)s * COLS + lane * 2);
            acc.x += w * hv.x; acc.y += w * hv.y;
        }
        st2v(z + (size_t)row * COLS + lane * 2, acc);
    }
}

// ---------------- MFMA bf16 GEMM: C[M,256] = A[M,K] @ B[K,256] (+epilogues) ----------------
// Tile 128x256 (full N -> A fetched once), BK=64, 512 threads = 8 waves of 64x64.
// MODE 0: C = A@B + bias
// MODE 1: C = relu(aggin*scale + shift) + A@B   (block-1 projection residual)
// TA = ushort(bf16) or float (converted during staging).
// LDS XOR swizzle (row&7)<<4 on 16B segments: conflict-free stage + <=2-way frag reads.

template<typename TA, int K, int MODE>
__global__ __launch_bounds__(512) void mgemm_k(const TA* __restrict__ A, const unsigned short* __restrict__ Bt,
                                               const float* __restrict__ bias, unsigned short* __restrict__ C,
                                               const float* __restrict__ scale, const float* __restrict__ shift,
                                               const unsigned short* __restrict__ aggin, int M) {
    __shared__ char Al[128 * 128];   // 128 rows x 64 bf16 (128 B/row)
    __shared__ char Bl[256 * 128];   // 256 rows x 64 bf16
    const int tid = threadIdx.x;
    const int lane = tid & 63;
    const int wid = tid >> 6;
    const int wm = wid >> 2;         // 0..1 : 64-row slab
    const int wn = wid & 3;          // 0..3 : 64-col slab
    const int row0 = blockIdx.x * 128;

    f32x4 acc[4][4];
#pragma unroll
    for (int i = 0; i < 4; i++)
#pragma unroll
        for (int j = 0; j < 4; j++) acc[i][j] = (f32x4){0.f, 0.f, 0.f, 0.f};

    for (int kt = 0; kt < K; kt += 64) {
        // stage A tile (16 KB, 2 passes x 512 thr x 16 B)
#pragma unroll
        for (int p = 0; p < 2; p++) {
            int idx = p * 512 + tid;
            int r = idx >> 3, seg = idx & 7;
            int grow = row0 + r;
            uint4 v = make_uint4(0u, 0u, 0u, 0u);
            if (grow < M) {
                if constexpr (sizeof(TA) == 2) {
                    v = *reinterpret_cast<const uint4*>((const unsigned short*)A + (size_t)grow * K + kt + seg * 8);
                } else {
                    const float* ap = (const float*)A + (size_t)grow * K + kt + seg * 8;
                    float4 f0 = *reinterpret_cast<const float4*>(ap);
                    float4 f1 = *reinterpret_cast<const float4*>(ap + 4);
                    union { unsigned short u[8]; uint4 v4; } cv;
                    cv.u[0] = f2b(f0.x); cv.u[1] = f2b(f0.y); cv.u[2] = f2b(f0.z); cv.u[3] = f2b(f0.w);
                    cv.u[4] = f2b(f1.x); cv.u[5] = f2b(f1.y); cv.u[6] = f2b(f1.z); cv.u[7] = f2b(f1.w);
                    v = cv.v4;
                }
            }
            *reinterpret_cast<uint4*>(Al + r * 128 + ((seg ^ (r & 7)) * 16)) = v;
        }
        // stage Bt tile (32 KB, 4 passes)
#pragma unroll
        for (int p = 0; p < 4; p++) {
            int idx = p * 512 + tid;
            int r = idx >> 3, seg = idx & 7;
            uint4 v = *reinterpret_cast<const uint4*>(Bt + (size_t)r * K + kt + seg * 8);
            *reinterpret_cast<uint4*>(Bl + r * 128 + ((seg ^ (r & 7)) * 16)) = v;
        }
        __syncthreads();

#pragma unroll
        for (int ks = 0; ks < 2; ks++) {
            bf16x8 af[4], bfr[4];
#pragma unroll
            for (int mf = 0; mf < 4; mf++) {
                int r = wm * 64 + mf * 16 + (lane & 15);
                int seg = ks * 4 + (lane >> 4);
                af[mf] = *reinterpret_cast<const bf16x8*>(Al + r * 128 + ((seg ^ (r & 7)) * 16));
            }
#pragma unroll
            for (int nf = 0; nf < 4; nf++) {
                int r = wn * 64 + nf * 16 + (lane & 15);
                int seg = ks * 4 + (lane >> 4);
                bfr[nf] = *reinterpret_cast<const bf16x8*>(Bl + r * 128 + ((seg ^ (r & 7)) * 16));
            }
#pragma unroll
            for (int mf = 0; mf < 4; mf++)
#pragma unroll
                for (int nf = 0; nf < 4; nf++)
                    acc[mf][nf] = __builtin_amdgcn_mfma_f32_16x16x32_bf16(af[mf], bfr[nf], acc[mf][nf], 0, 0, 0);
        }
        __syncthreads();
    }

    // epilogue: lane l, reg r -> row = 4*(l>>4)+r, col = l&15 (within each 16x16 frag)
#pragma unroll
    for (int mf = 0; mf < 4; mf++) {
#pragma unroll
        for (int r = 0; r < 4; r++) {
            int grow = row0 + wm * 64 + mf * 16 + (lane >> 4) * 4 + r;
            if (grow >= M) continue;
#pragma unroll
            for (int nf = 0; nf < 4; nf++) {
                int col = wn * 64 + nf * 16 + (lane & 15);
                float v = acc[mf][nf][r];
                if (MODE == 0) {
                    v += bias[col];
                } else {
                    float ag = b2f(aggin[(size_t)grow * HD + col]);
                    v = fmaxf(fmaf(ag, scale[col], shift[col]), 0.f) + v;
                }
                C[(size_t)grow * HD + col] = f2b(v);
            }
        }
    }
}

// ---------------- BatchNorm ----------------

__global__ __launch_bounds__(256) void bn_stats_k(const unsigned short* __restrict__ agg, float* __restrict__ sums) {
    const int c = threadIdx.x;
    const int rs = blockIdx.x * 196;
    const int re = min(rs + 196, NN);
    float s = 0.f, q = 0.f;
    for (int r = rs; r < re; r++) {
        float v = ld1(agg + (size_t)r * HD + c);
        s += v; q += v * v;
    }
    atomicAdd(&sums[c], s);
    atomicAdd(&sums[HD + c], q);
}

__global__ void bn_fin_k(const float* __restrict__ sums, const float* __restrict__ g,
                         const float* __restrict__ be, float* __restrict__ sc, float* __restrict__ sh) {
    int c = threadIdx.x;
    float m = sums[c] * (1.0f / NN);
    float v = sums[HD + c] * (1.0f / NN) - m * m;
    float s = g[c] * rsqrtf(v + BNEPS);
    sc[c] = s;
    sh[c] = be[c] - m * s;
}

__global__ __launch_bounds__(256) void epi_k(const unsigned short* __restrict__ agg,
                                             const unsigned short* __restrict__ res,
                                             const float* __restrict__ scp, const float* __restrict__ shp,
                                             unsigned short* __restrict__ out) {
    const size_t total = (size_t)NN * (HD / 4);
    size_t i = (size_t)blockIdx.x * 256 + threadIdx.x;
    const size_t stride = (size_t)gridDim.x * 256;
    for (; i < total; i += stride) {
        int cq = ((int)(i & 63)) * 4;
        float4 a = ld4v(agg + i * 4);
        float4 r = ld4v(res + i * 4);
        float4 sc = *reinterpret_cast<const float4*>(scp + cq);
        float4 sh = *reinterpret_cast<const float4*>(shp + cq);
        float4 o;
        o.x = fmaxf(fmaf(a.x, sc.x, sh.x), 0.f) + r.x;
        o.y = fmaxf(fmaf(a.y, sc.y, sh.y), 0.f) + r.y;
        o.z = fmaxf(fmaf(a.z, sc.z, sh.z), 0.f) + r.z;
        o.w = fmaxf(fmaf(a.w, sc.w, sh.w), 0.f) + r.w;
        st4v(out + i * 4, o);
    }
}

// ---------------- pooling head ----------------

__global__ __launch_bounds__(256) void pool_sum_k(const unsigned short* __restrict__ h,
                                                  const int* __restrict__ batch,
                                                  float* __restrict__ pooled) {
    const int c = threadIdx.x;
    const int rs = blockIdx.x * 256;
    if (rs >= NN) return;
    const int re = min(rs + 256, NN);
    float acc = 0.f;
    int cur = batch[rs];
    for (int r = rs; r < re; r++) {
        int g = batch[r];
        if (g != cur) { atomicAdd(&pooled[(size_t)cur * HD + c], acc); acc = 0.f; cur = g; }
        acc += ld1(h + (size_t)r * HD + c);
    }
    atomicAdd(&pooled[(size_t)cur * HD + c], acc);
}

// counts from binary search on the SORTED batch array — no atomics.
__global__ void pool_out_k(const float* __restrict__ pooled, const int* __restrict__ batch,
                           const float* __restrict__ Wl, const float* __restrict__ bl,
                           float* __restrict__ out) {
    int g = threadIdx.x;
    if (g < NG) {
        auto lb = [&](int val) {
            int lo = 0, hi = NN;
            while (lo < hi) { int mid = (lo + hi) >> 1; if (batch[mid] < val) lo = mid + 1; else hi = mid; }
            return lo;
        };
        int c0 = lb(g), c1 = lb(g + 1);
        float cn = fmaxf((float)(c1 - c0), 1.0f);
        float s = 0.f;
        for (int c = 0; c < HD; c++) s += pooled[(size_t)g * HD + c] * Wl[c];
        out[g] = s / cn + bl[0];
    }
}

// ---------------- launcher ----------------

static inline size_t alignup(size_t x) { return (x + 255) & ~size_t(255); }

extern "C" void kernel_launch(void* const* d_in, const int* in_sizes, int n_in,
                              void* d_out, int out_size, void* d_ws, size_t ws_size,
                              hipStream_t stream) {
    const float* x    = (const float*)d_in[0];
    const int*   ei   = (const int*)d_in[1];
    const int*   bat  = (const int*)d_in[2];
    const float* W1   = (const float*)d_in[3];
    const float* bi1  = (const float*)d_in[4];
    const float* g1   = (const float*)d_in[5];
    const float* be1  = (const float*)d_in[6];
    const float* P1   = (const float*)d_in[7];
    const float* W2   = (const float*)d_in[8];
    const float* bi2  = (const float*)d_in[9];
    const float* g2   = (const float*)d_in[10];
    const float* be2  = (const float*)d_in[11];
    const float* W3   = (const float*)d_in[12];
    const float* bi3  = (const float*)d_in[13];
    const float* g3   = (const float*)d_in[14];
    const float* be3  = (const float*)d_in[15];
    const float* W4   = (const float*)d_in[16];
    const float* bi4  = (const float*)d_in[17];
    const float* g4   = (const float*)d_in[18];
    const float* be4  = (const float*)d_in[19];
    const float* Wl   = (const float*)d_in[20];
    const float* bl   = (const float*)d_in[21];
    float* out = (float*)d_out;

    const int* e_src = ei;
    const int* e_dst = ei + NE;

    typedef unsigned short ST;
    char* p = (char*)d_ws;
    auto alloc = [&](size_t bytes) { char* q = p; p += alignup(bytes); return q; };
    ST*    fb0     = (ST*)alloc((size_t)NN * HD * sizeof(ST));
    ST*    fb1     = (ST*)alloc((size_t)NN * HD * sizeof(ST));
    ST*    fb2     = (ST*)alloc((size_t)NN * HD * sizeof(ST));
    int*   cnt     = (int*)alloc((size_t)NN * 4);
    int*   cursor  = (int*)alloc((size_t)NN * 4);
    float* dis     = (float*)alloc((size_t)NN * 4);
    float* selfw   = (float*)alloc((size_t)NN * 4);
    int*   rowptr  = (int*)alloc((size_t)(NN + 1) * 4);
    int*   csr_src = (int*)alloc((size_t)NE * 4);
    float* csr_w   = (float*)alloc((size_t)NE * 4);
    int*   partials= (int*)alloc(128 * 4);
    float* sums    = (float*)alloc(2 * HD * 4);
    float* bnsc    = (float*)alloc(HD * 4);
    float* bnsh    = (float*)alloc(HD * 4);
    float* pooled  = (float*)alloc((size_t)NG * HD * 4);
    ST*    w1t     = (ST*)alloc(256 * 128 * sizeof(ST));
    ST*    p1t     = (ST*)alloc(256 * 128 * sizeof(ST));
    ST*    w2t     = (ST*)alloc(256 * 256 * sizeof(ST));
    ST*    w3t     = (ST*)alloc(256 * 256 * sizeof(ST));
    ST*    w4t     = (ST*)alloc(256 * 256 * sizeof(ST));

    const int NB = (NN + 1023) / 1024;  // 98
    const int GG = (NN + 127) / 128;    // 782 gemm blocks

    // ---- weight prep (independent of graph) ----
    wt_k<<<128, 256, 0, stream>>>(W1, w1t, 128);
    wt_k<<<128, 256, 0, stream>>>(P1, p1t, 128);
    wt_k<<<256, 256, 0, stream>>>(W2, w2t, 256);
    wt_k<<<256, 256, 0, stream>>>(W3, w3t, 256);
    wt_k<<<256, 256, 0, stream>>>(W4, w4t, 256);

    // ---- graph preprocessing ----
    hipMemsetAsync(cnt, 0, (size_t)NN * 4, stream);
    hipMemsetAsync(cursor, 0, (size_t)NN * 4, stream);
    count_deg_k<<<(NE + 255) / 256, 256, 0, stream>>>(e_dst, cnt);
    node_prep_k<<<(NN + 255) / 256, 256, 0, stream>>>(cnt, dis, selfw);
    scan_reduce_k<<<NB, 1024, 0, stream>>>(cnt, partials);
    scan_partials_k<<<1, 64, 0, stream>>>(partials, NB);
    scan_write_k<<<NB, 1024, 0, stream>>>(cnt, partials, rowptr);
    fill_csr_k<<<(NE + 255) / 256, 256, 0, stream>>>(e_src, e_dst, rowptr, cursor, dis, csr_src, csr_w);

    // ---- block 1 (x:128 -> 256, projection residual) ----
    spmm_k<float, 128><<<NN / 4, 256, 0, stream>>>(x, rowptr, csr_src, csr_w, selfw, fb0);
    mgemm_k<ST, 128, 0><<<GG, 512, 0, stream>>>(fb0, w1t, bi1, fb2, nullptr, nullptr, nullptr, NN);
    hipMemsetAsync(sums, 0, 2 * HD * 4, stream);
    bn_stats_k<<<511, 256, 0, stream>>>(fb2, sums);
    bn_fin_k<<<1, 256, 0, stream>>>(sums, g1, be1, bnsc, bnsh);
    mgemm_k<float, 128, 1><<<GG, 512, 0, stream>>>(x, p1t, nullptr, fb1, bnsc, bnsh, fb2, NN);
    // h1 = fb1

    // ---- block 2 ----
    spmm_k<ST, 256><<<NN / 4, 256, 0, stream>>>(fb1, rowptr, csr_src, csr_w, selfw, fb0);
    mgemm_k<ST, 256, 0><<<GG, 512, 0, stream>>>(fb0, w2t, bi2, fb2, nullptr, nullptr, nullptr, NN);
    hipMemsetAsync(sums, 0, 2 * HD * 4, stream);
    bn_stats_k<<<511, 256, 0, stream>>>(fb2, sums);
    bn_fin_k<<<1, 256, 0, stream>>>(sums, g2, be2, bnsc, bnsh);
    epi_k<<<4096, 256, 0, stream>>>(fb2, fb1, bnsc, bnsh, fb0);
    // h2 = fb0

    // ---- block 3 ----
    spmm_k<ST, 256><<<NN / 4, 256, 0, stream>>>(fb0, rowptr, csr_src, csr_w, selfw, fb1);
    mgemm_k<ST, 256, 0><<<GG, 512, 0, stream>>>(fb1, w3t, bi3, fb2, nullptr, nullptr, nullptr, NN);
    hipMemsetAsync(sums, 0, 2 * HD * 4, stream);
    bn_stats_k<<<511, 256, 0, stream>>>(fb2, sums);
    bn_fin_k<<<1, 256, 0, stream>>>(sums, g3, be3, bnsc, bnsh);
    epi_k<<<4096, 256, 0, stream>>>(fb2, fb0, bnsc, bnsh, fb1);
    // h3 = fb1

    // ---- block 4 ----
    spmm_k<ST, 256><<<NN / 4, 256, 0, stream>>>(fb1, rowptr, csr_src, csr_w, selfw, fb0);
    mgemm_k<ST, 256, 0><<<GG, 512, 0, stream>>>(fb0, w4t, bi4, fb2, nullptr, nullptr, nullptr, NN);
    hipMemsetAsync(sums, 0, 2 * HD * 4, stream);
    bn_stats_k<<<511, 256, 0, stream>>>(fb2, sums);
    bn_fin_k<<<1, 256, 0, stream>>>(sums, g4, be4, bnsc, bnsh);
    epi_k<<<4096, 256, 0, stream>>>(fb2, fb1, bnsc, bnsh, fb0);
    // h4 = fb0

    // ---- pooling head ----
    hipMemsetAsync(pooled, 0, (size_t)NG * HD * 4, stream);
    pool_sum_k<<<(NN + 255) / 256, 256, 0, stream>>>(fb0, bat, pooled);
    pool_out_k<<<1, 64, 0, stream>>>(pooled, bat, Wl, bl, out);
}

// Round 5
// 1059.248 us; speedup vs baseline: 2.1177x; 1.1410x over previous
//
#include <hip/hip_runtime.h>
#include <cstdint>
#include <cstddef>

#define NN 100000
#define NE 1000000
#define FIN 128
#define HD 256
#define NG 64
#define BNEPS 1e-5f

typedef unsigned short ushort_t;
typedef __attribute__((ext_vector_type(8))) short bf16x8;
typedef __attribute__((ext_vector_type(4))) float f32x4;

// ---------- bf16<->f32 helpers (storage is raw bf16 bits in ushort) ----------

__device__ inline float b2f(unsigned short u) {
    union { float f; unsigned int i; } x; x.i = ((unsigned int)u) << 16; return x.f;
}
__device__ inline unsigned short f2b(float f) {
    union { float f; unsigned int i; } x; x.f = f;
    unsigned int r = x.i + 0x7FFFu + ((x.i >> 16) & 1u);
    return (unsigned short)(r >> 16);
}
__device__ inline float  ld1(const unsigned short* p) { return b2f(*p); }
__device__ inline float4 ld4v(const unsigned short* p) {
    ushort4 u = *(const ushort4*)p;
    return make_float4(b2f(u.x), b2f(u.y), b2f(u.z), b2f(u.w));
}
__device__ inline float2 ld2v(const float* p) { return *(const float2*)p; }
__device__ inline float2 ld2v(const unsigned short* p) {
    ushort2 u = *(const ushort2*)p;
    return make_float2(b2f(u.x), b2f(u.y));
}
__device__ inline void st4v(unsigned short* p, float4 v) {
    ushort4 u; u.x = f2b(v.x); u.y = f2b(v.y); u.z = f2b(v.z); u.w = f2b(v.w);
    *(ushort4*)p = u;
}
__device__ inline void st2v(unsigned short* p, float2 v) {
    ushort2 u; u.x = f2b(v.x); u.y = f2b(v.y);
    *(ushort2*)p = u;
}

// ---------------- graph preprocessing ----------------

__global__ __launch_bounds__(256) void count_deg_k(const int* __restrict__ dst, int* __restrict__ cnt) {
    int e = blockIdx.x * 256 + threadIdx.x;
    if (e < NE) atomicAdd(&cnt[dst[e]], 1);
}

__global__ __launch_bounds__(256) void node_prep_k(const int* __restrict__ cnt,
                                                   float* __restrict__ dis, float* __restrict__ selfw) {
    int i = blockIdx.x * 256 + threadIdx.x;
    if (i < NN) {
        float d = (float)cnt[i] + 1.0f;
        dis[i] = rsqrtf(d);
        selfw[i] = 1.0f / d;
    }
}

__global__ __launch_bounds__(1024) void scan_reduce_k(const int* __restrict__ cnt, int* __restrict__ partials) {
    __shared__ int sh[1024];
    int i = blockIdx.x * 1024 + threadIdx.x;
    sh[threadIdx.x] = (i < NN) ? cnt[i] : 0;
    __syncthreads();
    for (int off = 512; off > 0; off >>= 1) {
        if (threadIdx.x < off) sh[threadIdx.x] += sh[threadIdx.x + off];
        __syncthreads();
    }
    if (threadIdx.x == 0) partials[blockIdx.x] = sh[0];
}

__global__ void scan_partials_k(int* partials, int nb) {
    if (threadIdx.x == 0 && blockIdx.x == 0) {
        int run = 0;
        for (int b = 0; b < nb; b++) { int v = partials[b]; partials[b] = run; run += v; }
    }
}

__global__ __launch_bounds__(1024) void scan_write_k(const int* __restrict__ cnt,
                                                     const int* __restrict__ partials,
                                                     int* __restrict__ rowptr) {
    __shared__ int sh[1024];
    int i = blockIdx.x * 1024 + threadIdx.x;
    int v = (i < NN) ? cnt[i] : 0;
    sh[threadIdx.x] = v;
    __syncthreads();
    for (int off = 1; off < 1024; off <<= 1) {
        int t = (threadIdx.x >= off) ? sh[threadIdx.x - off] : 0;
        __syncthreads();
        sh[threadIdx.x] += t;
        __syncthreads();
    }
    if (i < NN) rowptr[i] = partials[blockIdx.x] + sh[threadIdx.x] - v;
    if (i == NN - 1) rowptr[NN] = partials[blockIdx.x] + sh[threadIdx.x];
}

// CSR packed as int2 {src, weight_bits}: one 8B load per edge in the SpMM.
__global__ __launch_bounds__(256) void fill_csr_k(const int* __restrict__ src, const int* __restrict__ dst,
                                                  const int* __restrict__ rowptr, int* __restrict__ cursor,
                                                  const float* __restrict__ dis,
                                                  int2* __restrict__ csr) {
    int e = blockIdx.x * 256 + threadIdx.x;
    if (e < NE) {
        int d = dst[e], s = src[e];
        int pos = rowptr[d] + atomicAdd(&cursor[d], 1);
        float w = dis[s] * dis[d];
        csr[pos] = make_int2(s, __float_as_int(w));
    }
}

// ---------------- SpMM: z[i,:] = selfw[i]*h[i,:] + sum_e w_e * h[src_e,:] ----------------
// Edge loop unrolled x4 with all gathers issued before the FMA chain -> 4 outstanding
// 512B gathers per wave (latency hiding for the random-access pattern).

template<typename SIN, int COLS>
__global__ __launch_bounds__(256) void spmm_k(const SIN* __restrict__ h,
                                              const int* __restrict__ rowptr,
                                              const int2* __restrict__ csr,
                                              const float* __restrict__ selfw,
                                              unsigned short* __restrict__ z) {
    const int lane = threadIdx.x & 63;
    const int row = blockIdx.x * 4 + (threadIdx.x >> 6);
    if (row >= NN) return;
    if constexpr (COLS == 256) {
        float4 a = ld4v(h + (size_t)row * COLS + lane * 4);
        float sw = selfw[row];
        float4 acc = make_float4(a.x * sw, a.y * sw, a.z * sw, a.w * sw);
        int e = rowptr[row];
        const int e1 = rowptr[row + 1];
        for (; e + 4 <= e1; e += 4) {
            int2 c0 = csr[e], c1 = csr[e + 1], c2 = csr[e + 2], c3 = csr[e + 3];
            float4 h0 = ld4v(h + (size_t)c0.x * COLS + lane * 4);
            float4 h1 = ld4v(h + (size_t)c1.x * COLS + lane * 4);
            float4 h2 = ld4v(h + (size_t)c2.x * COLS + lane * 4);
            float4 h3 = ld4v(h + (size_t)c3.x * COLS + lane * 4);
            float w0 = __int_as_float(c0.y), w1 = __int_as_float(c1.y);
            float w2 = __int_as_float(c2.y), w3 = __int_as_float(c3.y);
            acc.x += w0 * h0.x; acc.y += w0 * h0.y; acc.z += w0 * h0.z; acc.w += w0 * h0.w;
            acc.x += w1 * h1.x; acc.y += w1 * h1.y; acc.z += w1 * h1.z; acc.w += w1 * h1.w;
            acc.x += w2 * h2.x; acc.y += w2 * h2.y; acc.z += w2 * h2.z; acc.w += w2 * h2.w;
            acc.x += w3 * h3.x; acc.y += w3 * h3.y; acc.z += w3 * h3.z; acc.w += w3 * h3.w;
        }
        for (; e < e1; e++) {
            int2 c = csr[e];
            float w = __int_as_float(c.y);
            float4 hv = ld4v(h + (size_t)c.x * COLS + lane * 4);
            acc.x += w * hv.x; acc.y += w * hv.y; acc.z += w * hv.z; acc.w += w * hv.w;
        }
        st4v(z + (size_t)row * COLS + lane * 4, acc);
    } else {
        float2 a = ld2v(h + (size_t)row * COLS + lane * 2);
        float sw = selfw[row];
        float2 acc = make_float2(a.x * sw, a.y * sw);
        int e = rowptr[row];
        const int e1 = rowptr[row + 1];
        for (; e + 4 <= e1; e += 4) {
            int2 c0 = csr[e], c1 = csr[e + 1], c2 = csr[e + 2], c3 = csr[e + 3];
            float2 h0 = ld2v(h + (size_t)c0.x * COLS + lane * 2);
            float2 h1 = ld2v(h + (size_t)c1.x * COLS + lane * 2);
            float2 h2 = ld2v(h + (size_t)c2.x * COLS + lane * 2);
            float2 h3 = ld2v(h + (size_t)c3.x * COLS + lane * 2);
            float w0 = __int_as_float(c0.y), w1 = __int_as_float(c1.y);
            float w2 = __int_as_float(c2.y), w3 = __int_as_float(c3.y);
            acc.x += w0 * h0.x; acc.y += w0 * h0.y;
            acc.x += w1 * h1.x; acc.y += w1 * h1.y;
            acc.x += w2 * h2.x; acc.y += w2 * h2.y;
            acc.x += w3 * h3.x; acc.y += w3 * h3.y;
        }
        for (; e < e1; e++) {
            int2 c = csr[e];
            float w = __int_as_float(c.y);
            float2 hv = ld2v(h + (size_t)c.x * COLS + lane * 2);
            acc.x += w * hv.x; acc.y += w * hv.y;
        }
        st2v(z + (size_t)row * COLS + lane * 2, acc);
    }
}

// ---- weight prep: W[K][256] fp32 -> Bt[256][K] bf16 (pre-transposed, N-major) ----
__global__ __launch_bounds__(256) void wt_k(const float* __restrict__ W, unsigned short* __restrict__ Bt, int K) {
    int i = blockIdx.x * 256 + threadIdx.x;
    if (i < K * 256) {
        int k = i >> 8, n = i & 255;
        Bt[n * K + k] = f2b(W[k * 256 + n]);
    }
}

// ---------------- MFMA bf16 GEMM: C[M,256] = A[M,K] @ B[K,256] (+epilogues) ----------------
// Tile 128x256, BK=64, 512 threads = 8 waves of 64x64.
// MODE 0: C = A@B + bias
// MODE 1: C = relu(aggin*scale + shift) + A@B   (block-1 projection residual)

template<typename TA, int K, int MODE>
__global__ __launch_bounds__(512) void mgemm_k(const TA* __restrict__ A, const unsigned short* __restrict__ Bt,
                                               const float* __restrict__ bias, unsigned short* __restrict__ C,
                                               const float* __restrict__ scale, const float* __restrict__ shift,
                                               const unsigned short* __restrict__ aggin, int M) {
    __shared__ char Al[128 * 128];   // 128 rows x 64 bf16 (128 B/row)
    __shared__ char Bl[256 * 128];   // 256 rows x 64 bf16
    const int tid = threadIdx.x;
    const int lane = tid & 63;
    const int wid = tid >> 6;
    const int wm = wid >> 2;         // 0..1 : 64-row slab
    const int wn = wid & 3;          // 0..3 : 64-col slab
    const int row0 = blockIdx.x * 128;

    f32x4 acc[4][4];
#pragma unroll
    for (int i = 0; i < 4; i++)
#pragma unroll
        for (int j = 0; j < 4; j++) acc[i][j] = (f32x4){0.f, 0.f, 0.f, 0.f};

    for (int kt = 0; kt < K; kt += 64) {
#pragma unroll
        for (int p = 0; p < 2; p++) {
            int idx = p * 512 + tid;
            int r = idx >> 3, seg = idx & 7;
            int grow = row0 + r;
            uint4 v = make_uint4(0u, 0u, 0u, 0u);
            if (grow < M) {
                if constexpr (sizeof(TA) == 2) {
                    v = *reinterpret_cast<const uint4*>((const unsigned short*)A + (size_t)grow * K + kt + seg * 8);
                } else {
                    const float* ap = (const float*)A + (size_t)grow * K + kt + seg * 8;
                    float4 f0 = *reinterpret_cast<const float4*>(ap);
                    float4 f1 = *reinterpret_cast<const float4*>(ap + 4);
                    union { unsigned short u[8]; uint4 v4; } cv;
                    cv.u[0] = f2b(f0.x); cv.u[1] = f2b(f0.y); cv.u[2] = f2b(f0.z); cv.u[3] = f2b(f0.w);
                    cv.u[4] = f2b(f1.x); cv.u[5] = f2b(f1.y); cv.u[6] = f2b(f1.z); cv.u[7] = f2b(f1.w);
                    v = cv.v4;
                }
            }
            *reinterpret_cast<uint4*>(Al + r * 128 + ((seg ^ (r & 7)) * 16)) = v;
        }
#pragma unroll
        for (int p = 0; p < 4; p++) {
            int idx = p * 512 + tid;
            int r = idx >> 3, seg = idx & 7;
            uint4 v = *reinterpret_cast<const uint4*>(Bt + (size_t)r * K + kt + seg * 8);
            *reinterpret_cast<uint4*>(Bl + r * 128 + ((seg ^ (r & 7)) * 16)) = v;
        }
        __syncthreads();

#pragma unroll
        for (int ks = 0; ks < 2; ks++) {
            bf16x8 af[4], bfr[4];
#pragma unroll
            for (int mf = 0; mf < 4; mf++) {
                int r = wm * 64 + mf * 16 + (lane & 15);
                int seg = ks * 4 + (lane >> 4);
                af[mf] = *reinterpret_cast<const bf16x8*>(Al + r * 128 + ((seg ^ (r & 7)) * 16));
            }
#pragma unroll
            for (int nf = 0; nf < 4; nf++) {
                int r = wn * 64 + nf * 16 + (lane & 15);
                int seg = ks * 4 + (lane >> 4);
                bfr[nf] = *reinterpret_cast<const bf16x8*>(Bl + r * 128 + ((seg ^ (r & 7)) * 16));
            }
#pragma unroll
            for (int mf = 0; mf < 4; mf++)
#pragma unroll
                for (int nf = 0; nf < 4; nf++)
                    acc[mf][nf] = __builtin_amdgcn_mfma_f32_16x16x32_bf16(af[mf], bfr[nf], acc[mf][nf], 0, 0, 0);
        }
        __syncthreads();
    }

#pragma unroll
    for (int mf = 0; mf < 4; mf++) {
#pragma unroll
        for (int r = 0; r < 4; r++) {
            int grow = row0 + wm * 64 + mf * 16 + (lane >> 4) * 4 + r;
            if (grow >= M) continue;
#pragma unroll
            for (int nf = 0; nf < 4; nf++) {
                int col = wn * 64 + nf * 16 + (lane & 15);
                float v = acc[mf][nf][r];
                if (MODE == 0) {
                    v += bias[col];
                } else {
                    float ag = b2f(aggin[(size_t)grow * HD + col]);
                    v = fmaxf(fmaf(ag, scale[col], shift[col]), 0.f) + v;
                }
                C[(size_t)grow * HD + col] = f2b(v);
            }
        }
    }
}

// ---------------- BatchNorm ----------------

__global__ __launch_bounds__(256) void bn_stats_k(const unsigned short* __restrict__ agg, float* __restrict__ sums) {
    const int c = threadIdx.x;
    const int rs = blockIdx.x * 196;
    const int re = min(rs + 196, NN);
    float s = 0.f, q = 0.f;
    for (int r = rs; r < re; r++) {
        float v = ld1(agg + (size_t)r * HD + c);
        s += v; q += v * v;
    }
    atomicAdd(&sums[c], s);
    atomicAdd(&sums[HD + c], q);
}

__global__ void bn_fin_k(const float* __restrict__ sums, const float* __restrict__ g,
                         const float* __restrict__ be, float* __restrict__ sc, float* __restrict__ sh) {
    int c = threadIdx.x;
    float m = sums[c] * (1.0f / NN);
    float v = sums[HD + c] * (1.0f / NN) - m * m;
    float s = g[c] * rsqrtf(v + BNEPS);
    sc[c] = s;
    sh[c] = be[c] - m * s;
}

__global__ __launch_bounds__(256) void epi_k(const unsigned short* __restrict__ agg,
                                             const unsigned short* __restrict__ res,
                                             const float* __restrict__ scp, const float* __restrict__ shp,
                                             unsigned short* __restrict__ out) {
    const size_t total = (size_t)NN * (HD / 4);
    size_t i = (size_t)blockIdx.x * 256 + threadIdx.x;
    const size_t stride = (size_t)gridDim.x * 256;
    for (; i < total; i += stride) {
        int cq = ((int)(i & 63)) * 4;
        float4 a = ld4v(agg + i * 4);
        float4 r = ld4v(res + i * 4);
        float4 sc = *reinterpret_cast<const float4*>(scp + cq);
        float4 sh = *reinterpret_cast<const float4*>(shp + cq);
        float4 o;
        o.x = fmaxf(fmaf(a.x, sc.x, sh.x), 0.f) + r.x;
        o.y = fmaxf(fmaf(a.y, sc.y, sh.y), 0.f) + r.y;
        o.z = fmaxf(fmaf(a.z, sc.z, sh.z), 0.f) + r.z;
        o.w = fmaxf(fmaf(a.w, sc.w, sh.w), 0.f) + r.w;
        st4v(out + i * 4, o);
    }
}

// ---------------- pooling head ----------------

__global__ __launch_bounds__(256) void pool_sum_k(const unsigned short* __restrict__ h,
                                                  const int* __restrict__ batch,
                                                  float* __restrict__ pooled) {
    const int c = threadIdx.x;
    const int rs = blockIdx.x * 256;
    if (rs >= NN) return;
    const int re = min(rs + 256, NN);
    float acc = 0.f;
    int cur = batch[rs];
    for (int r = rs; r < re; r++) {
        int g = batch[r];
        if (g != cur) { atomicAdd(&pooled[(size_t)cur * HD + c], acc); acc = 0.f; cur = g; }
        acc += ld1(h + (size_t)r * HD + c);
    }
    atomicAdd(&pooled[(size_t)cur * HD + c], acc);
}

// counts from binary search on the SORTED batch array — no atomics.
__global__ void pool_out_k(const float* __restrict__ pooled, const int* __restrict__ batch,
                           const float* __restrict__ Wl, const float* __restrict__ bl,
                           float* __restrict__ out) {
    int g = threadIdx.x;
    if (g < NG) {
        auto lb = [&](int val) {
            int lo = 0, hi = NN;
            while (lo < hi) { int mid = (lo + hi) >> 1; if (batch[mid] < val) lo = mid + 1; else hi = mid; }
            return lo;
        };
        int c0 = lb(g), c1 = lb(g + 1);
        float cn = fmaxf((float)(c1 - c0), 1.0f);
        float s = 0.f;
        for (int c = 0; c < HD; c++) s += pooled[(size_t)g * HD + c] * Wl[c];
        out[g] = s / cn + bl[0];
    }
}

// ---------------- launcher ----------------

static inline size_t alignup(size_t x) { return (x + 255) & ~size_t(255); }

extern "C" void kernel_launch(void* const* d_in, const int* in_sizes, int n_in,
                              void* d_out, int out_size, void* d_ws, size_t ws_size,
                              hipStream_t stream) {
    const float* x    = (const float*)d_in[0];
    const int*   ei   = (const int*)d_in[1];
    const int*   bat  = (const int*)d_in[2];
    const float* W1   = (const float*)d_in[3];
    const float* bi1  = (const float*)d_in[4];
    const float* g1   = (const float*)d_in[5];
    const float* be1  = (const float*)d_in[6];
    const float* P1   = (const float*)d_in[7];
    const float* W2   = (const float*)d_in[8];
    const float* bi2  = (const float*)d_in[9];
    const float* g2   = (const float*)d_in[10];
    const float* be2  = (const float*)d_in[11];
    const float* W3   = (const float*)d_in[12];
    const float* bi3  = (const float*)d_in[13];
    const float* g3   = (const float*)d_in[14];
    const float* be3  = (const float*)d_in[15];
    const float* W4   = (const float*)d_in[16];
    const float* bi4  = (const float*)d_in[17];
    const float* g4   = (const float*)d_in[18];
    const float* be4  = (const float*)d_in[19];
    const float* Wl   = (const float*)d_in[20];
    const float* bl   = (const float*)d_in[21];
    float* out = (float*)d_out;

    const int* e_src = ei;
    const int* e_dst = ei + NE;

    typedef unsigned short ST;
    char* p = (char*)d_ws;
    auto alloc = [&](size_t bytes) { char* q = p; p += alignup(bytes); return q; };
    ST*    fb0     = (ST*)alloc((size_t)NN * HD * sizeof(ST));
    ST*    fb1     = (ST*)alloc((size_t)NN * HD * sizeof(ST));
    ST*    fb2     = (ST*)alloc((size_t)NN * HD * sizeof(ST));
    int*   cnt     = (int*)alloc((size_t)NN * 4);
    int*   cursor  = (int*)alloc((size_t)NN * 4);
    float* dis     = (float*)alloc((size_t)NN * 4);
    float* selfw   = (float*)alloc((size_t)NN * 4);
    int*   rowptr  = (int*)alloc((size_t)(NN + 1) * 4);
    int2*  csr     = (int2*)alloc((size_t)NE * 8);
    int*   partials= (int*)alloc(128 * 4);
    float* sums    = (float*)alloc(2 * HD * 4);
    float* bnsc    = (float*)alloc(HD * 4);
    float* bnsh    = (float*)alloc(HD * 4);
    float* pooled  = (float*)alloc((size_t)NG * HD * 4);
    ST*    w1t     = (ST*)alloc(256 * 128 * sizeof(ST));
    ST*    p1t     = (ST*)alloc(256 * 128 * sizeof(ST));
    ST*    w2t     = (ST*)alloc(256 * 256 * sizeof(ST));
    ST*    w3t     = (ST*)alloc(256 * 256 * sizeof(ST));
    ST*    w4t     = (ST*)alloc(256 * 256 * sizeof(ST));

    const int NB = (NN + 1023) / 1024;  // 98
    const int GG = (NN + 127) / 128;    // 782 gemm blocks

    // ---- weight prep (independent of graph) ----
    wt_k<<<128, 256, 0, stream>>>(W1, w1t, 128);
    wt_k<<<128, 256, 0, stream>>>(P1, p1t, 128);
    wt_k<<<256, 256, 0, stream>>>(W2, w2t, 256);
    wt_k<<<256, 256, 0, stream>>>(W3, w3t, 256);
    wt_k<<<256, 256, 0, stream>>>(W4, w4t, 256);

    // ---- graph preprocessing ----
    hipMemsetAsync(cnt, 0, (size_t)NN * 4, stream);
    hipMemsetAsync(cursor, 0, (size_t)NN * 4, stream);
    count_deg_k<<<(NE + 255) / 256, 256, 0, stream>>>(e_dst, cnt);
    node_prep_k<<<(NN + 255) / 256, 256, 0, stream>>>(cnt, dis, selfw);
    scan_reduce_k<<<NB, 1024, 0, stream>>>(cnt, partials);
    scan_partials_k<<<1, 64, 0, stream>>>(partials, NB);
    scan_write_k<<<NB, 1024, 0, stream>>>(cnt, partials, rowptr);
    fill_csr_k<<<(NE + 255) / 256, 256, 0, stream>>>(e_src, e_dst, rowptr, cursor, dis, csr);

    // ---- block 1 (x:128 -> 256, projection residual) ----
    spmm_k<float, 128><<<NN / 4, 256, 0, stream>>>(x, rowptr, csr, selfw, fb0);
    mgemm_k<ST, 128, 0><<<GG, 512, 0, stream>>>(fb0, w1t, bi1, fb2, nullptr, nullptr, nullptr, NN);
    hipMemsetAsync(sums, 0, 2 * HD * 4, stream);
    bn_stats_k<<<511, 256, 0, stream>>>(fb2, sums);
    bn_fin_k<<<1, 256, 0, stream>>>(sums, g1, be1, bnsc, bnsh);
    mgemm_k<float, 128, 1><<<GG, 512, 0, stream>>>(x, p1t, nullptr, fb1, bnsc, bnsh, fb2, NN);
    // h1 = fb1

    // ---- block 2 ----
    spmm_k<ST, 256><<<NN / 4, 256, 0, stream>>>(fb1, rowptr, csr, selfw, fb0);
    mgemm_k<ST, 256, 0><<<GG, 512, 0, stream>>>(fb0, w2t, bi2, fb2, nullptr, nullptr, nullptr, NN);
    hipMemsetAsync(sums, 0, 2 * HD * 4, stream);
    bn_stats_k<<<511, 256, 0, stream>>>(fb2, sums);
    bn_fin_k<<<1, 256, 0, stream>>>(sums, g2, be2, bnsc, bnsh);
    epi_k<<<4096, 256, 0, stream>>>(fb2, fb1, bnsc, bnsh, fb0);
    // h2 = fb0

    // ---- block 3 ----
    spmm_k<ST, 256><<<NN / 4, 256, 0, stream>>>(fb0, rowptr, csr, selfw, fb1);
    mgemm_k<ST, 256, 0><<<GG, 512, 0, stream>>>(fb1, w3t, bi3, fb2, nullptr, nullptr, nullptr, NN);
    hipMemsetAsync(sums, 0, 2 * HD * 4, stream);
    bn_stats_k<<<511, 256, 0, stream>>>(fb2, sums);
    bn_fin_k<<<1, 256, 0, stream>>>(sums, g3, be3, bnsc, bnsh);
    epi_k<<<4096, 256, 0, stream>>>(fb2, fb0, bnsc, bnsh, fb1);
    // h3 = fb1

    // ---- block 4 ----
    spmm_k<ST, 256><<<NN / 4, 256, 0, stream>>>(fb1, rowptr, csr, selfw, fb0);
    mgemm_k<ST, 256, 0><<<GG, 512, 0, stream>>>(fb0, w4t, bi4, fb2, nullptr, nullptr, nullptr, NN);
    hipMemsetAsync(sums, 0, 2 * HD * 4, stream);
    bn_stats_k<<<511, 256, 0, stream>>>(fb2, sums);
    bn_fin_k<<<1, 256, 0, stream>>>(sums, g4, be4, bnsc, bnsh);
    epi_k<<<4096, 256, 0, stream>>>(fb2, fb1, bnsc, bnsh, fb0);
    // h4 = fb0

    // ---- pooling head ----
    hipMemsetAsync(pooled, 0, (size_t)NG * HD * 4, stream);
    pool_sum_k<<<(NN + 255) / 256, 256, 0, stream>>>(fb0, bat, pooled);
    pool_out_k<<<1, 64, 0, stream>>>(pooled, bat, Wl, bl, out);
}

// Round 6
// 925.504 us; speedup vs baseline: 2.4238x; 1.1445x over previous
//
#include <hip/hip_runtime.h>
#include <cstdint>
#include <cstddef>

#define NN 100000
#define NE 1000000
#define FIN 128
#define HD 256
#define NG 64
#define BNEPS 1e-5f

typedef unsigned short ushort_t;
typedef __attribute__((ext_vector_type(8))) short bf16x8;
typedef __attribute__((ext_vector_type(4))) float f32x4;

// ---------- bf16<->f32 helpers (storage is raw bf16 bits in ushort) ----------

__device__ inline float b2f(unsigned short u) {
    union { float f; unsigned int i; } x; x.i = ((unsigned int)u) << 16; return x.f;
}
__device__ inline unsigned short f2b(float f) {
    union { float f; unsigned int i; } x; x.f = f;
    unsigned int r = x.i + 0x7FFFu + ((x.i >> 16) & 1u);
    return (unsigned short)(r >> 16);
}
__device__ inline float  ld1(const unsigned short* p) { return b2f(*p); }
__device__ inline float4 ld4v(const unsigned short* p) {
    ushort4 u = *(const ushort4*)p;
    return make_float4(b2f(u.x), b2f(u.y), b2f(u.z), b2f(u.w));
}
__device__ inline float2 ld2v(const unsigned short* p) {
    ushort2 u = *(const ushort2*)p;
    return make_float2(b2f(u.x), b2f(u.y));
}
__device__ inline void st4v(unsigned short* p, float4 v) {
    ushort4 u; u.x = f2b(v.x); u.y = f2b(v.y); u.z = f2b(v.z); u.w = f2b(v.w);
    *(ushort4*)p = u;
}
__device__ inline void st2v(unsigned short* p, float2 v) {
    ushort2 u; u.x = f2b(v.x); u.y = f2b(v.y);
    *(ushort2*)p = u;
}

// ---------------- graph preprocessing ----------------

__global__ __launch_bounds__(256) void count_deg_k(const int* __restrict__ dst, int* __restrict__ cnt) {
    int e = blockIdx.x * 256 + threadIdx.x;
    if (e < NE) atomicAdd(&cnt[dst[e]], 1);
}

__global__ __launch_bounds__(256) void node_prep_k(const int* __restrict__ cnt,
                                                   float* __restrict__ dis, float* __restrict__ selfw) {
    int i = blockIdx.x * 256 + threadIdx.x;
    if (i < NN) {
        float d = (float)cnt[i] + 1.0f;
        dis[i] = rsqrtf(d);
        selfw[i] = 1.0f / d;
    }
}

__global__ __launch_bounds__(1024) void scan_reduce_k(const int* __restrict__ cnt, int* __restrict__ partials) {
    __shared__ int sh[1024];
    int i = blockIdx.x * 1024 + threadIdx.x;
    sh[threadIdx.x] = (i < NN) ? cnt[i] : 0;
    __syncthreads();
    for (int off = 512; off > 0; off >>= 1) {
        if (threadIdx.x < off) sh[threadIdx.x] += sh[threadIdx.x + off];
        __syncthreads();
    }
    if (threadIdx.x == 0) partials[blockIdx.x] = sh[0];
}

__global__ void scan_partials_k(int* partials, int nb) {
    if (threadIdx.x == 0 && blockIdx.x == 0) {
        int run = 0;
        for (int b = 0; b < nb; b++) { int v = partials[b]; partials[b] = run; run += v; }
    }
}

__global__ __launch_bounds__(1024) void scan_write_k(const int* __restrict__ cnt,
                                                     const int* __restrict__ partials,
                                                     int* __restrict__ rowptr) {
    __shared__ int sh[1024];
    int i = blockIdx.x * 1024 + threadIdx.x;
    int v = (i < NN) ? cnt[i] : 0;
    sh[threadIdx.x] = v;
    __syncthreads();
    for (int off = 1; off < 1024; off <<= 1) {
        int t = (threadIdx.x >= off) ? sh[threadIdx.x - off] : 0;
        __syncthreads();
        sh[threadIdx.x] += t;
        __syncthreads();
    }
    if (i < NN) rowptr[i] = partials[blockIdx.x] + sh[threadIdx.x] - v;
    if (i == NN - 1) rowptr[NN] = partials[blockIdx.x] + sh[threadIdx.x];
}

// CSR packed as int2 {src, weight_bits}: one 8B load per edge in the SpMM.
__global__ __launch_bounds__(256) void fill_csr_k(const int* __restrict__ src, const int* __restrict__ dst,
                                                  const int* __restrict__ rowptr, int* __restrict__ cursor,
                                                  const float* __restrict__ dis,
                                                  int2* __restrict__ csr) {
    int e = blockIdx.x * 256 + threadIdx.x;
    if (e < NE) {
        int d = dst[e], s = src[e];
        int pos = rowptr[d] + atomicAdd(&cursor[d], 1);
        float w = dis[s] * dis[d];
        csr[pos] = make_int2(s, __float_as_int(w));
    }
}

// ---- x (fp32 [N,128]) -> bf16: halves block-1 gather bytes ----
__global__ __launch_bounds__(256) void x2b_k(const float* __restrict__ x, unsigned short* __restrict__ xb) {
    int i = blockIdx.x * 256 + threadIdx.x;     // one float4 per thread
    if (i < NN * FIN / 4) {
        float4 v = *reinterpret_cast<const float4*>(x + (size_t)i * 4);
        ushort4 u; u.x = f2b(v.x); u.y = f2b(v.y); u.z = f2b(v.z); u.w = f2b(v.w);
        *reinterpret_cast<ushort4*>(xb + (size_t)i * 4) = u;
    }
}

// ---- weight prep, all 5 in one launch: W[K][256] fp32 -> Bt[256][K] bf16 ----
__global__ __launch_bounds__(256) void wt_all_k(const float* __restrict__ W1, const float* __restrict__ P1,
                                                const float* __restrict__ W2, const float* __restrict__ W3,
                                                const float* __restrict__ W4,
                                                unsigned short* __restrict__ w1t, unsigned short* __restrict__ p1t,
                                                unsigned short* __restrict__ w2t, unsigned short* __restrict__ w3t,
                                                unsigned short* __restrict__ w4t) {
    int b = blockIdx.x;
    const float* W; unsigned short* Bt; int K; int base;
    if (b < 128)      { W = W1; Bt = w1t; K = 128; base = b; }
    else if (b < 256) { W = P1; Bt = p1t; K = 128; base = b - 128; }
    else if (b < 512) { W = W2; Bt = w2t; K = 256; base = b - 256; }
    else if (b < 768) { W = W3; Bt = w3t; K = 256; base = b - 512; }
    else              { W = W4; Bt = w4t; K = 256; base = b - 768; }
    int i = base * 256 + threadIdx.x;
    if (i < K * 256) {
        int k = i >> 8, n = i & 255;
        Bt[n * K + k] = f2b(W[k * 256 + n]);
    }
}

// ---------------- SpMM: z[i,:] = selfw[i]*h[i,:] + sum_e w_e * h[src_e,:] ----------------
// bf16 input always; edge loop unrolled x4 (4 outstanding gathers/wave).

template<int COLS>
__global__ __launch_bounds__(256) void spmm_k(const unsigned short* __restrict__ h,
                                              const int* __restrict__ rowptr,
                                              const int2* __restrict__ csr,
                                              const float* __restrict__ selfw,
                                              unsigned short* __restrict__ z) {
    const int lane = threadIdx.x & 63;
    const int row = blockIdx.x * 4 + (threadIdx.x >> 6);
    if (row >= NN) return;
    if constexpr (COLS == 256) {
        float4 a = ld4v(h + (size_t)row * COLS + lane * 4);
        float sw = selfw[row];
        float4 acc = make_float4(a.x * sw, a.y * sw, a.z * sw, a.w * sw);
        int e = rowptr[row];
        const int e1 = rowptr[row + 1];
        for (; e + 4 <= e1; e += 4) {
            int2 c0 = csr[e], c1 = csr[e + 1], c2 = csr[e + 2], c3 = csr[e + 3];
            float4 h0 = ld4v(h + (size_t)c0.x * COLS + lane * 4);
            float4 h1 = ld4v(h + (size_t)c1.x * COLS + lane * 4);
            float4 h2 = ld4v(h + (size_t)c2.x * COLS + lane * 4);
            float4 h3 = ld4v(h + (size_t)c3.x * COLS + lane * 4);
            float w0 = __int_as_float(c0.y), w1 = __int_as_float(c1.y);
            float w2 = __int_as_float(c2.y), w3 = __int_as_float(c3.y);
            acc.x += w0 * h0.x; acc.y += w0 * h0.y; acc.z += w0 * h0.z; acc.w += w0 * h0.w;
            acc.x += w1 * h1.x; acc.y += w1 * h1.y; acc.z += w1 * h1.z; acc.w += w1 * h1.w;
            acc.x += w2 * h2.x; acc.y += w2 * h2.y; acc.z += w2 * h2.z; acc.w += w2 * h2.w;
            acc.x += w3 * h3.x; acc.y += w3 * h3.y; acc.z += w3 * h3.z; acc.w += w3 * h3.w;
        }
        for (; e < e1; e++) {
            int2 c = csr[e];
            float w = __int_as_float(c.y);
            float4 hv = ld4v(h + (size_t)c.x * COLS + lane * 4);
            acc.x += w * hv.x; acc.y += w * hv.y; acc.z += w * hv.z; acc.w += w * hv.w;
        }
        st4v(z + (size_t)row * COLS + lane * 4, acc);
    } else {
        float2 a = ld2v(h + (size_t)row * COLS + lane * 2);
        float sw = selfw[row];
        float2 acc = make_float2(a.x * sw, a.y * sw);
        int e = rowptr[row];
        const int e1 = rowptr[row + 1];
        for (; e + 4 <= e1; e += 4) {
            int2 c0 = csr[e], c1 = csr[e + 1], c2 = csr[e + 2], c3 = csr[e + 3];
            float2 h0 = ld2v(h + (size_t)c0.x * COLS + lane * 2);
            float2 h1 = ld2v(h + (size_t)c1.x * COLS + lane * 2);
            float2 h2 = ld2v(h + (size_t)c2.x * COLS + lane * 2);
            float2 h3 = ld2v(h + (size_t)c3.x * COLS + lane * 2);
            float w0 = __int_as_float(c0.y), w1 = __int_as_float(c1.y);
            float w2 = __int_as_float(c2.y), w3 = __int_as_float(c3.y);
            acc.x += w0 * h0.x; acc.y += w0 * h0.y;
            acc.x += w1 * h1.x; acc.y += w1 * h1.y;
            acc.x += w2 * h2.x; acc.y += w2 * h2.y;
            acc.x += w3 * h3.x; acc.y += w3 * h3.y;
        }
        for (; e < e1; e++) {
            int2 c = csr[e];
            float w = __int_as_float(c.y);
            float2 hv = ld2v(h + (size_t)c.x * COLS + lane * 2);
            acc.x += w * hv.x; acc.y += w * hv.y;
        }
        st2v(z + (size_t)row * COLS + lane * 2, acc);
    }
}

// ---------------- MFMA bf16 GEMM: C[M,256] = A[M,K] @ B[K,256] (+epilogues) ----------------
// Tile 128x256, BK=64, 512 threads = 8 waves of 64x64.
// MODE 0: C = A@B + bias, and (fused) per-column BN partial sums (s, s^2) -> global atomics
// MODE 1: C = relu(aggin*scale + shift) + A@B   (block-1 projection residual)

template<typename TA, int K, int MODE>
__global__ __launch_bounds__(512) void mgemm_k(const TA* __restrict__ A, const unsigned short* __restrict__ Bt,
                                               const float* __restrict__ bias, unsigned short* __restrict__ C,
                                               const float* __restrict__ scale, const float* __restrict__ shift,
                                               const unsigned short* __restrict__ aggin,
                                               float* __restrict__ sums, int M) {
    __shared__ char Al[128 * 128];   // 128 rows x 64 bf16 (128 B/row)
    __shared__ char Bl[256 * 128];   // 256 rows x 64 bf16
    const int tid = threadIdx.x;
    const int lane = tid & 63;
    const int wid = tid >> 6;
    const int wm = wid >> 2;         // 0..1 : 64-row slab
    const int wn = wid & 3;          // 0..3 : 64-col slab
    const int row0 = blockIdx.x * 128;

    f32x4 acc[4][4];
#pragma unroll
    for (int i = 0; i < 4; i++)
#pragma unroll
        for (int j = 0; j < 4; j++) acc[i][j] = (f32x4){0.f, 0.f, 0.f, 0.f};

    for (int kt = 0; kt < K; kt += 64) {
#pragma unroll
        for (int p = 0; p < 2; p++) {
            int idx = p * 512 + tid;
            int r = idx >> 3, seg = idx & 7;
            int grow = row0 + r;
            uint4 v = make_uint4(0u, 0u, 0u, 0u);
            if (grow < M) {
                if constexpr (sizeof(TA) == 2) {
                    v = *reinterpret_cast<const uint4*>((const unsigned short*)A + (size_t)grow * K + kt + seg * 8);
                } else {
                    const float* ap = (const float*)A + (size_t)grow * K + kt + seg * 8;
                    float4 f0 = *reinterpret_cast<const float4*>(ap);
                    float4 f1 = *reinterpret_cast<const float4*>(ap + 4);
                    union { unsigned short u[8]; uint4 v4; } cv;
                    cv.u[0] = f2b(f0.x); cv.u[1] = f2b(f0.y); cv.u[2] = f2b(f0.z); cv.u[3] = f2b(f0.w);
                    cv.u[4] = f2b(f1.x); cv.u[5] = f2b(f1.y); cv.u[6] = f2b(f1.z); cv.u[7] = f2b(f1.w);
                    v = cv.v4;
                }
            }
            *reinterpret_cast<uint4*>(Al + r * 128 + ((seg ^ (r & 7)) * 16)) = v;
        }
#pragma unroll
        for (int p = 0; p < 4; p++) {
            int idx = p * 512 + tid;
            int r = idx >> 3, seg = idx & 7;
            uint4 v = *reinterpret_cast<const uint4*>(Bt + (size_t)r * K + kt + seg * 8);
            *reinterpret_cast<uint4*>(Bl + r * 128 + ((seg ^ (r & 7)) * 16)) = v;
        }
        __syncthreads();

#pragma unroll
        for (int ks = 0; ks < 2; ks++) {
            bf16x8 af[4], bfr[4];
#pragma unroll
            for (int mf = 0; mf < 4; mf++) {
                int r = wm * 64 + mf * 16 + (lane & 15);
                int seg = ks * 4 + (lane >> 4);
                af[mf] = *reinterpret_cast<const bf16x8*>(Al + r * 128 + ((seg ^ (r & 7)) * 16));
            }
#pragma unroll
            for (int nf = 0; nf < 4; nf++) {
                int r = wn * 64 + nf * 16 + (lane & 15);
                int seg = ks * 4 + (lane >> 4);
                bfr[nf] = *reinterpret_cast<const bf16x8*>(Bl + r * 128 + ((seg ^ (r & 7)) * 16));
            }
#pragma unroll
            for (int mf = 0; mf < 4; mf++)
#pragma unroll
                for (int nf = 0; nf < 4; nf++)
                    acc[mf][nf] = __builtin_amdgcn_mfma_f32_16x16x32_bf16(af[mf], bfr[nf], acc[mf][nf], 0, 0, 0);
        }
        __syncthreads();
    }

    if (MODE == 0) {
        // epilogue + fused BN stats: LDS per-block column partials, then global atomics
        float* slds = reinterpret_cast<float*>(Al);   // 512 floats: [s 256][q 256]
        slds[tid] = 0.f;
        __syncthreads();
#pragma unroll
        for (int nf = 0; nf < 4; nf++) {
            int col = wn * 64 + nf * 16 + (lane & 15);
            float bb = bias[col];
            float s = 0.f, q = 0.f;
#pragma unroll
            for (int mf = 0; mf < 4; mf++) {
#pragma unroll
                for (int r = 0; r < 4; r++) {
                    int grow = row0 + wm * 64 + mf * 16 + (lane >> 4) * 4 + r;
                    if (grow >= M) continue;
                    float v = acc[mf][nf][r] + bb;
                    C[(size_t)grow * HD + col] = f2b(v);
                    s += v; q += v * v;
                }
            }
            atomicAdd(&slds[col], s);
            atomicAdd(&slds[256 + col], q);
        }
        __syncthreads();
        atomicAdd(&sums[tid], slds[tid]);
    } else {
#pragma unroll
        for (int mf = 0; mf < 4; mf++) {
#pragma unroll
            for (int r = 0; r < 4; r++) {
                int grow = row0 + wm * 64 + mf * 16 + (lane >> 4) * 4 + r;
                if (grow >= M) continue;
#pragma unroll
                for (int nf = 0; nf < 4; nf++) {
                    int col = wn * 64 + nf * 16 + (lane & 15);
                    float v = acc[mf][nf][r];
                    float ag = b2f(aggin[(size_t)grow * HD + col]);
                    v = fmaxf(fmaf(ag, scale[col], shift[col]), 0.f) + v;
                    C[(size_t)grow * HD + col] = f2b(v);
                }
            }
        }
    }
}

// ---------------- BatchNorm finalize + epilogue ----------------

__global__ void bn_fin_k(const float* __restrict__ sums, const float* __restrict__ g,
                         const float* __restrict__ be, float* __restrict__ sc, float* __restrict__ sh) {
    int c = threadIdx.x;
    float m = sums[c] * (1.0f / NN);
    float v = sums[HD + c] * (1.0f / NN) - m * m;
    float s = g[c] * rsqrtf(v + BNEPS);
    sc[c] = s;
    sh[c] = be[c] - m * s;
}

__global__ __launch_bounds__(256) void epi_k(const unsigned short* __restrict__ agg,
                                             const unsigned short* __restrict__ res,
                                             const float* __restrict__ scp, const float* __restrict__ shp,
                                             unsigned short* __restrict__ out) {
    const size_t total = (size_t)NN * (HD / 4);
    size_t i = (size_t)blockIdx.x * 256 + threadIdx.x;
    const size_t stride = (size_t)gridDim.x * 256;
    for (; i < total; i += stride) {
        int cq = ((int)(i & 63)) * 4;
        float4 a = ld4v(agg + i * 4);
        float4 r = ld4v(res + i * 4);
        float4 sc = *reinterpret_cast<const float4*>(scp + cq);
        float4 sh = *reinterpret_cast<const float4*>(shp + cq);
        float4 o;
        o.x = fmaxf(fmaf(a.x, sc.x, sh.x), 0.f) + r.x;
        o.y = fmaxf(fmaf(a.y, sc.y, sh.y), 0.f) + r.y;
        o.z = fmaxf(fmaf(a.z, sc.z, sh.z), 0.f) + r.z;
        o.w = fmaxf(fmaf(a.w, sc.w, sh.w), 0.f) + r.w;
        st4v(out + i * 4, o);
    }
}

// ---------------- pooling head ----------------

__global__ __launch_bounds__(256) void pool_sum_k(const unsigned short* __restrict__ h,
                                                  const int* __restrict__ batch,
                                                  float* __restrict__ pooled) {
    const int c = threadIdx.x;
    const int rs = blockIdx.x * 256;
    if (rs >= NN) return;
    const int re = min(rs + 256, NN);
    float acc = 0.f;
    int cur = batch[rs];
    for (int r = rs; r < re; r++) {
        int g = batch[r];
        if (g != cur) { atomicAdd(&pooled[(size_t)cur * HD + c], acc); acc = 0.f; cur = g; }
        acc += ld1(h + (size_t)r * HD + c);
    }
    atomicAdd(&pooled[(size_t)cur * HD + c], acc);
}

// counts from binary search on the SORTED batch array — no atomics.
__global__ void pool_out_k(const float* __restrict__ pooled, const int* __restrict__ batch,
                           const float* __restrict__ Wl, const float* __restrict__ bl,
                           float* __restrict__ out) {
    int g = threadIdx.x;
    if (g < NG) {
        auto lb = [&](int val) {
            int lo = 0, hi = NN;
            while (lo < hi) { int mid = (lo + hi) >> 1; if (batch[mid] < val) lo = mid + 1; else hi = mid; }
            return lo;
        };
        int c0 = lb(g), c1 = lb(g + 1);
        float cn = fmaxf((float)(c1 - c0), 1.0f);
        float s = 0.f;
        for (int c = 0; c < HD; c++) s += pooled[(size_t)g * HD + c] * Wl[c];
        out[g] = s / cn + bl[0];
    }
}

// ---------------- launcher ----------------

static inline size_t alignup(size_t x) { return (x + 255) & ~size_t(255); }

extern "C" void kernel_launch(void* const* d_in, const int* in_sizes, int n_in,
                              void* d_out, int out_size, void* d_ws, size_t ws_size,
                              hipStream_t stream) {
    const float* x    = (const float*)d_in[0];
    const int*   ei   = (const int*)d_in[1];
    const int*   bat  = (const int*)d_in[2];
    const float* W1   = (const float*)d_in[3];
    const float* bi1  = (const float*)d_in[4];
    const float* g1   = (const float*)d_in[5];
    const float* be1  = (const float*)d_in[6];
    const float* P1   = (const float*)d_in[7];
    const float* W2   = (const float*)d_in[8];
    const float* bi2  = (const float*)d_in[9];
    const float* g2   = (const float*)d_in[10];
    const float* be2  = (const float*)d_in[11];
    const float* W3   = (const float*)d_in[12];
    const float* bi3  = (const float*)d_in[13];
    const float* g3   = (const float*)d_in[14];
    const float* be3  = (const float*)d_in[15];
    const float* W4   = (const float*)d_in[16];
    const float* bi4  = (const float*)d_in[17];
    const float* g4   = (const float*)d_in[18];
    const float* be4  = (const float*)d_in[19];
    const float* Wl   = (const float*)d_in[20];
    const float* bl   = (const float*)d_in[21];
    float* out = (float*)d_out;

    const int* e_src = ei;
    const int* e_dst = ei + NE;

    typedef unsigned short ST;
    char* p = (char*)d_ws;
    auto alloc = [&](size_t bytes) { char* q = p; p += alignup(bytes); return q; };
    ST*    fb0     = (ST*)alloc((size_t)NN * HD * sizeof(ST));
    ST*    fb1     = (ST*)alloc((size_t)NN * HD * sizeof(ST));
    ST*    fb2     = (ST*)alloc((size_t)NN * HD * sizeof(ST));
    ST*    xb      = (ST*)alloc((size_t)NN * FIN * sizeof(ST));
    float* dis     = (float*)alloc((size_t)NN * 4);
    float* selfw   = (float*)alloc((size_t)NN * 4);
    int*   rowptr  = (int*)alloc((size_t)(NN + 1) * 4);
    int2*  csr     = (int2*)alloc((size_t)NE * 8);
    int*   partials= (int*)alloc(128 * 4);
    float* bnsc    = (float*)alloc(HD * 4);
    float* bnsh    = (float*)alloc(HD * 4);
    ST*    w1t     = (ST*)alloc(256 * 128 * sizeof(ST));
    ST*    p1t     = (ST*)alloc(256 * 128 * sizeof(ST));
    ST*    w2t     = (ST*)alloc(256 * 256 * sizeof(ST));
    ST*    w3t     = (ST*)alloc(256 * 256 * sizeof(ST));
    ST*    w4t     = (ST*)alloc(256 * 256 * sizeof(ST));
    // ---- single zeroed region: cnt | cursor | sums[4] | pooled ----
    size_t zbytes = (size_t)NN * 4 + (size_t)NN * 4 + 4 * 2 * HD * 4 + (size_t)NG * HD * 4;
    char*  zbase   = alloc(zbytes);
    int*   cnt     = (int*)zbase;
    int*   cursor  = (int*)(zbase + (size_t)NN * 4);
    float* sums1   = (float*)(zbase + (size_t)NN * 8);
    float* sums2   = sums1 + 2 * HD;
    float* sums3   = sums2 + 2 * HD;
    float* sums4   = sums3 + 2 * HD;
    float* pooled  = sums4 + 2 * HD;

    const int NB = (NN + 1023) / 1024;  // 98
    const int GG = (NN + 127) / 128;    // 782 gemm blocks

    hipMemsetAsync(zbase, 0, zbytes, stream);

    // ---- weight/x prep (independent of graph) ----
    wt_all_k<<<1024, 256, 0, stream>>>(W1, P1, W2, W3, W4, w1t, p1t, w2t, w3t, w4t);
    x2b_k<<<(NN * FIN / 4 + 255) / 256, 256, 0, stream>>>(x, xb);

    // ---- graph preprocessing ----
    count_deg_k<<<(NE + 255) / 256, 256, 0, stream>>>(e_dst, cnt);
    node_prep_k<<<(NN + 255) / 256, 256, 0, stream>>>(cnt, dis, selfw);
    scan_reduce_k<<<NB, 1024, 0, stream>>>(cnt, partials);
    scan_partials_k<<<1, 64, 0, stream>>>(partials, NB);
    scan_write_k<<<NB, 1024, 0, stream>>>(cnt, partials, rowptr);
    fill_csr_k<<<(NE + 255) / 256, 256, 0, stream>>>(e_src, e_dst, rowptr, cursor, dis, csr);

    // ---- block 1 (x:128 -> 256, projection residual) ----
    spmm_k<128><<<NN / 4, 256, 0, stream>>>(xb, rowptr, csr, selfw, fb0);
    mgemm_k<ST, 128, 0><<<GG, 512, 0, stream>>>(fb0, w1t, bi1, fb2, nullptr, nullptr, nullptr, sums1, NN);
    bn_fin_k<<<1, 256, 0, stream>>>(sums1, g1, be1, bnsc, bnsh);
    mgemm_k<float, 128, 1><<<GG, 512, 0, stream>>>(x, p1t, nullptr, fb1, bnsc, bnsh, fb2, nullptr, NN);
    // h1 = fb1

    // ---- block 2 ----
    spmm_k<256><<<NN / 4, 256, 0, stream>>>(fb1, rowptr, csr, selfw, fb0);
    mgemm_k<ST, 256, 0><<<GG, 512, 0, stream>>>(fb0, w2t, bi2, fb2, nullptr, nullptr, nullptr, sums2, NN);
    bn_fin_k<<<1, 256, 0, stream>>>(sums2, g2, be2, bnsc, bnsh);
    epi_k<<<4096, 256, 0, stream>>>(fb2, fb1, bnsc, bnsh, fb0);
    // h2 = fb0

    // ---- block 3 ----
    spmm_k<256><<<NN / 4, 256, 0, stream>>>(fb0, rowptr, csr, selfw, fb1);
    mgemm_k<ST, 256, 0><<<GG, 512, 0, stream>>>(fb1, w3t, bi3, fb2, nullptr, nullptr, nullptr, sums3, NN);
    bn_fin_k<<<1, 256, 0, stream>>>(sums3, g3, be3, bnsc, bnsh);
    epi_k<<<4096, 256, 0, stream>>>(fb2, fb0, bnsc, bnsh, fb1);
    // h3 = fb1

    // ---- block 4 ----
    spmm_k<256><<<NN / 4, 256, 0, stream>>>(fb1, rowptr, csr, selfw, fb0);
    mgemm_k<ST, 256, 0><<<GG, 512, 0, stream>>>(fb0, w4t, bi4, fb2, nullptr, nullptr, nullptr, sums4, NN);
    bn_fin_k<<<1, 256, 0, stream>>>(sums4, g4, be4, bnsc, bnsh);
    epi_k<<<4096, 256, 0, stream>>>(fb2, fb1, bnsc, bnsh, fb0);
    // h4 = fb0

    // ---- pooling head ----
    pool_sum_k<<<(NN + 255) / 256, 256, 0, stream>>>(fb0, bat, pooled);
    pool_out_k<<<1, 64, 0, stream>>>(pooled, bat, Wl, bl, out);
}